// Round 8
// baseline (4012.317 us; speedup 1.0000x reference)
//
#include <hip/hip_runtime.h>

#define Bn 8
#define Mn 2048
#define Nn 2048
#define Cn 256
#define Np1 2049
#define Mp1 2049
#define UVS 2056                        /* padded u/v row stride (16B-aligned per batch) */
#define SINK_ITERS 20
#define NORM   (-8.3177661667193428f)   /* -log(4096) */
#define LOGBIN (-0.6931471805599453f)   /* log(2048) - log(4096) */
#define LOG2E  (1.4426950408889634f)
#define LN2    (0.6931471805599453f)
#define NORM2  (-12.0f)                 /* log2(1/4096), exact */
#define LOGBIN2 (-1.0f)                 /* LOGBIN * log2e, exact */
#define PNORM  (8.3177661667193428f)    /* -NORM */
#define KSH    32.0f                    /* K prescale: K = 2^(S2 - KSH) */
#define GRID_P 1024                     /* persistent grid: 4 blocks/CU x 256 CU */

/* device transcendental shorthands: v_exp_f32 = 2^x, v_log_f32 = log2(x) */
#define EXP2(x) __builtin_amdgcn_exp2f(x)
#define LOG2(x) __builtin_amdgcn_logf(x)

typedef __bf16 v8bf __attribute__((ext_vector_type(8)));
typedef float  v4f  __attribute__((ext_vector_type(4)));
typedef unsigned short v8u __attribute__((ext_vector_type(8)));

__device__ __forceinline__ float bf2f(unsigned short h){
  return __uint_as_float(((unsigned)h) << 16);
}
__device__ __forceinline__ unsigned short f2bf(float f){
  unsigned u = __float_as_uint(f);
  return (unsigned short)((u + 0x7FFFu + ((u >> 16) & 1u)) >> 16);
}
__device__ __forceinline__ float ldS(const float* p){ return *p; }
__device__ __forceinline__ float ldS(const unsigned short* p){ return bf2f(*p); }
__device__ __forceinline__ void  stS(float* p, float x){ *p = x; }
__device__ __forceinline__ void  stS(unsigned short* p, float x){ *p = f2bf(x); }

// online logsumexp accumulate (ln domain; fallback paths only)
__device__ __forceinline__ void ons(float x, float& m, float& s){
  if (x <= m) { s += __expf(x - m); }
  else        { s = s * __expf(m - x) + 1.0f; m = x; }
}
__device__ __forceinline__ void comb(float& m, float& s, float m2, float s2){
  if (m2 <= m) { s += s2 * __expf(m2 - m); }
  else         { s = s * __expf(m - m2) + s2; m = m2; }
}

// ---------------- fp32 -> bf16 convert (one v8 per thread, exact grid) ---------------------
__global__ void __launch_bounds__(256) conv_k(
    const float* __restrict__ in, unsigned short* __restrict__ out)
{
  size_t idx = (size_t)blockIdx.x * 256 + threadIdx.x;   // Bn*Mn*Cn/8 threads exactly
  const float* p = in + idx * 8;
  v4f a = *(const v4f*)p;
  v4f c = *(const v4f*)(p + 4);
  v8u o;
  #pragma unroll
  for (int e = 0; e < 4; ++e){ o[e] = f2bf(a[e]); o[e+4] = f2bf(c[e]); }
  *(v8u*)(out + idx * 8) = o;
}

// ---------------- GEMM (bf16 in): K = 2^(log2e*A.B^T - KSH), and K^T via LDS transpose -----
__global__ void __launch_bounds__(256) gemm_ke(
    const unsigned short* __restrict__ A, const unsigned short* __restrict__ Bm,
    unsigned short* __restrict__ K, unsigned short* __restrict__ KT)
{
  __shared__ unsigned short lt[4][64][65];           // 33.3 KB, wave-private 64x65 regions
  int wid  = (blockIdx.x * 256 + threadIdx.x) >> 6;  // 1 wave = one 64x64 tile
  int w    = (threadIdx.x >> 6) & 3;
  int lane = threadIdx.x & 63;
  int b  = wid >> 10;          // 32*32 = 1024 tiles per batch
  int tt = wid & 1023;
  int i0 = (tt >> 5) << 6;
  int j0 = (tt & 31) << 6;
  int ln = lane & 15, qd = lane >> 4;
  const unsigned short* Ab = A  + (size_t)b * Mn * Cn;
  const unsigned short* Bb = Bm + (size_t)b * Nn * Cn;

  v4f acc[4][4];
  #pragma unroll
  for (int r = 0; r < 4; ++r)
    #pragma unroll
    for (int c = 0; c < 4; ++c)
      #pragma unroll
      for (int e = 0; e < 4; ++e) acc[r][c][e] = 0.0f;

  #pragma unroll
  for (int k0 = 0; k0 < Cn; k0 += 32){
    int kk = k0 + qd * 8;
    v8bf af[4], bfr[4];
    #pragma unroll
    for (int r = 0; r < 4; ++r)
      af[r] = *(const v8bf*)(const void*)(Ab + (size_t)(i0 + r*16 + ln) * Cn + kk);
    #pragma unroll
    for (int c = 0; c < 4; ++c)
      bfr[c] = *(const v8bf*)(const void*)(Bb + (size_t)(j0 + c*16 + ln) * Cn + kk);
    #pragma unroll
    for (int r = 0; r < 4; ++r)
      #pragma unroll
      for (int c = 0; c < 4; ++c)
        acc[r][c] = __builtin_amdgcn_mfma_f32_16x16x32_bf16(af[r], bfr[c], acc[r][c], 0, 0, 0);
  }

  // epilogue 1: exp + write K, stage into LDS
  unsigned short* Kb = K + (size_t)b * Mn * Nn;
  #pragma unroll
  for (int r = 0; r < 4; ++r){
    #pragma unroll
    for (int e = 0; e < 4; ++e){
      int lr = r*16 + qd*4 + e;          // C/D: col=lane&15, row=quad*4+reg  [HW-verified]
      #pragma unroll
      for (int c = 0; c < 4; ++c){
        float x = fminf(acc[r][c][e] * LOG2E, 158.0f) - KSH;
        unsigned short hv = f2bf(EXP2(x));
        Kb[(size_t)(i0 + lr) * Nn + (j0 + c*16 + ln)] = hv;
        lt[w][lr][c*16 + ln] = hv;
      }
    }
  }
  // epilogue 2: transposed write to KT (tile lands at (j0, i0)); coalesced on ln
  unsigned short* Tb = KT + (size_t)b * Mn * Nn;
  #pragma unroll
  for (int r = 0; r < 4; ++r){
    #pragma unroll
    for (int e = 0; e < 4; ++e){
      int p = r*16 + qd*4 + e;
      #pragma unroll
      for (int c = 0; c < 4; ++c){
        int q = c*16 + ln;
        Tb[(size_t)(j0 + p) * Mn + (i0 + q)] = lt[w][q][p];
      }
    }
  }
}

// ---------------- two-level device-scope grid barrier (1024 blocks, 32 groups of 32) -------
// bar[0..31]=group counters, bar[32]=global counter, bar[33]=generation. Zeroed per launch.
// Agent-scope acq_rel atomics provide cross-XCD visibility (L2 wb/inv at coherence point).
// Bounded spin: a residency failure corrupts results (visible test fail), never hangs.
__device__ __forceinline__ void gbar(unsigned* bar){
  __syncthreads();
  if (threadIdx.x == 0){
    __threadfence();
    int grp = blockIdx.x >> 5;
    unsigned gen = __hip_atomic_load(bar + 33, __ATOMIC_RELAXED, __HIP_MEMORY_SCOPE_AGENT);
    unsigned a = __hip_atomic_fetch_add(bar + grp, 1u, __ATOMIC_ACQ_REL, __HIP_MEMORY_SCOPE_AGENT);
    if (a == 31u){
      unsigned g2 = __hip_atomic_fetch_add(bar + 32, 1u, __ATOMIC_ACQ_REL, __HIP_MEMORY_SCOPE_AGENT);
      if (g2 == 31u){
        #pragma unroll
        for (int i = 0; i < 32; ++i)
          __hip_atomic_store(bar + i, 0u, __ATOMIC_RELAXED, __HIP_MEMORY_SCOPE_AGENT);
        __hip_atomic_store(bar + 32, 0u, __ATOMIC_RELAXED, __HIP_MEMORY_SCOPE_AGENT);
        __hip_atomic_store(bar + 33, gen + 1u, __ATOMIC_RELEASE, __HIP_MEMORY_SCOPE_AGENT);
      }
    }
    int spins = 0;
    while (__hip_atomic_load(bar + 33, __ATOMIC_RELAXED, __HIP_MEMORY_SCOPE_AGENT) == gen){
      if (++spins > (1 << 20)) break;
      __builtin_amdgcn_s_sleep(2);
    }
    __threadfence();
  }
  __syncthreads();
}

// ---------------- persistent Sinkhorn half-pass: pure-FMA GEMV with shifted weights --------
// uout[i] = NORM2-KSH-mv - log2( sum_j K[i,j]*2^(v[j]-mv) + 2^(bin2+v[N]-KSH-mv) ), 4 rows/wave
__device__ __forceinline__ void half_u(
    const unsigned short* __restrict__ Kb, const float* __restrict__ vin,
    float* __restrict__ uout, int r0, int lane, float bin2, bool dustw)
{
  v4f w[8];
  #pragma unroll
  for (int q = 0; q < 4; ++q){
    int j0 = q * 512 + lane * 8;
    w[2*q]   = *(const v4f*)(vin + j0);
    w[2*q+1] = *(const v4f*)(vin + j0 + 4);
  }
  float mv = w[0][0];
  #pragma unroll
  for (int h = 0; h < 8; ++h)
    #pragma unroll
    for (int e = 0; e < 4; ++e) mv = fmaxf(mv, w[h][e]);
  #pragma unroll
  for (int off = 32; off > 0; off >>= 1) mv = fmaxf(mv, __shfl_xor(mv, off));
  #pragma unroll
  for (int h = 0; h < 8; ++h)
    #pragma unroll
    for (int e = 0; e < 4; ++e) w[h][e] = EXP2(w[h][e] - mv);
  float vN = vin[Nn];

  float acc[4][4];
  #pragma unroll
  for (int r = 0; r < 4; ++r)
    #pragma unroll
    for (int c = 0; c < 4; ++c) acc[r][c] = 0.0f;
  #pragma unroll
  for (int q = 0; q < 4; ++q){
    int j0 = q * 512 + lane * 8;
    v8u kr[4];
    #pragma unroll
    for (int r = 0; r < 4; ++r)
      kr[r] = *(const v8u*)(Kb + (size_t)(r0 + r) * Nn + j0);
    #pragma unroll
    for (int r = 0; r < 4; ++r){
      acc[r][0] += bf2f(kr[r][0]) * w[2*q][0];
      acc[r][1] += bf2f(kr[r][1]) * w[2*q][1];
      acc[r][2] += bf2f(kr[r][2]) * w[2*q][2];
      acc[r][3] += bf2f(kr[r][3]) * w[2*q][3];
      acc[r][0] += bf2f(kr[r][4]) * w[2*q+1][0];
      acc[r][1] += bf2f(kr[r][5]) * w[2*q+1][1];
      acc[r][2] += bf2f(kr[r][6]) * w[2*q+1][2];
      acc[r][3] += bf2f(kr[r][7]) * w[2*q+1][3];
    }
  }
  float s[4];
  #pragma unroll
  for (int r = 0; r < 4; ++r){
    s[r] = (acc[r][0] + acc[r][1]) + (acc[r][2] + acc[r][3]);
    #pragma unroll
    for (int off = 32; off > 0; off >>= 1) s[r] += __shfl_xor(s[r], off);
  }
  if (lane == 0){
    float dustc = EXP2(bin2 + vN - KSH - mv);
    float base = NORM2 - KSH - mv;
    #pragma unroll
    for (int r = 0; r < 4; ++r) uout[r0 + r] = base - LOG2(s[r] + dustc);
  }
  if (dustw){
    // dustbin: uout[M] = LOGBIN2 - (bin2 + mv + log2( sum_j 2^(v[j]-mv) + 2^(vN-mv) ))
    float sw = 0.f;
    #pragma unroll
    for (int h = 0; h < 8; ++h) sw += (w[h][0] + w[h][1]) + (w[h][2] + w[h][3]);
    #pragma unroll
    for (int off = 32; off > 0; off >>= 1) sw += __shfl_xor(sw, off);
    if (lane == 0) uout[Mn] = LOGBIN2 - (bin2 + mv + LOG2(sw + EXP2(vN - mv)));
  }
}

// persistent kernel: all 20 iterations, grid barrier between half-passes.
// grid = 1024 blocks (4/CU, co-resident by __launch_bounds__(256,4), zero LDS).
__global__ void __launch_bounds__(256, 4) sink_k(
    const unsigned short* __restrict__ K, const unsigned short* __restrict__ KT,
    float* __restrict__ u, float* __restrict__ v,
    const float* __restrict__ binp, unsigned* __restrict__ bar)
{
  int g = blockIdx.x;
  int b = g >> 7;                          // 128 blocks per batch
  int wv = threadIdx.x >> 6;
  int lane = threadIdx.x & 63;
  int r0 = (g & 127) * 16 + wv * 4;        // this wave's 4 rows
  float bin2 = binp[0] * LOG2E;
  const unsigned short* Kb  = K  + (size_t)b * Mn * Nn;
  const unsigned short* KTb = KT + (size_t)b * Mn * Nn;
  float* ub = u + (size_t)b * UVS;
  float* vb = v + (size_t)b * UVS;
  bool dust = ((g & 127) == 0) && (wv == 3);   // one dustbin wave per batch
  for (int it = 0; it < SINK_ITERS; ++it){
    half_u(Kb, vb, ub, r0, lane, bin2, dust);  // u-update from v
    gbar(bar);
    half_u(KTb, ub, vb, r0, lane, bin2, dust); // v-update from u
    if (it != SINK_ITERS - 1) gbar(bar);       // final visibility via kernel end
  }
}

// ---------------- final: recompute fp32 scores via MFMA, fuse +u+v epilogue ----------------
__global__ void __launch_bounds__(256) final_g(
    const unsigned short* __restrict__ A, const unsigned short* __restrict__ Bm,
    float* __restrict__ out, const float* __restrict__ u, const float* __restrict__ v)
{
  int wid  = (blockIdx.x * 256 + threadIdx.x) >> 6;
  int lane = threadIdx.x & 63;
  int b  = wid >> 10;
  int tt = wid & 1023;
  int i0 = (tt >> 5) << 6;
  int j0 = (tt & 31) << 6;
  int ln = lane & 15, qd = lane >> 4;
  const unsigned short* Ab = A  + (size_t)b * Mn * Cn;
  const unsigned short* Bb = Bm + (size_t)b * Nn * Cn;

  v4f acc[4][4];
  #pragma unroll
  for (int r = 0; r < 4; ++r)
    #pragma unroll
    for (int c = 0; c < 4; ++c)
      #pragma unroll
      for (int e = 0; e < 4; ++e) acc[r][c][e] = 0.0f;

  #pragma unroll
  for (int k0 = 0; k0 < Cn; k0 += 32){
    int kk = k0 + qd * 8;
    v8bf af[4], bfr[4];
    #pragma unroll
    for (int r = 0; r < 4; ++r)
      af[r] = *(const v8bf*)(const void*)(Ab + (size_t)(i0 + r*16 + ln) * Cn + kk);
    #pragma unroll
    for (int c = 0; c < 4; ++c)
      bfr[c] = *(const v8bf*)(const void*)(Bb + (size_t)(j0 + c*16 + ln) * Cn + kk);
    #pragma unroll
    for (int r = 0; r < 4; ++r)
      #pragma unroll
      for (int c = 0; c < 4; ++c)
        acc[r][c] = __builtin_amdgcn_mfma_f32_16x16x32_bf16(af[r], bfr[c], acc[r][c], 0, 0, 0);
  }

  const float* ub = u + (size_t)b * UVS;
  const float* vp = v + (size_t)b * UVS;
  float vv[4];
  #pragma unroll
  for (int c = 0; c < 4; ++c) vv[c] = vp[j0 + c*16 + ln] * LN2;
  float* ob = out + (size_t)b * Mp1 * Np1;
  #pragma unroll
  for (int r = 0; r < 4; ++r){
    #pragma unroll
    for (int e = 0; e < 4; ++e){
      int row = i0 + r*16 + qd*4 + e;
      float uu = ub[row] * LN2 + PNORM;
      #pragma unroll
      for (int c = 0; c < 4; ++c)
        ob[(size_t)row * Np1 + (j0 + c*16 + ln)] = acc[r][c][e] + uu + vv[c];
    }
  }
}

// edges: out[b,M,j] and out[b,i,N] (score = bin)
__global__ void __launch_bounds__(256) fin_edge(
    float* __restrict__ out, const float* __restrict__ u,
    const float* __restrict__ v, const float* __restrict__ binp)
{
  int b = blockIdx.y;
  int t = blockIdx.x * 256 + threadIdx.x;
  float bin2 = binp[0] * LOG2E;
  const float* ub = u + (size_t)b * UVS;
  const float* vb = v + (size_t)b * UVS;
  float* ob = out + (size_t)b * Mp1 * Np1;
  if (t <= Nn){
    ob[(size_t)Mn * Np1 + t] = (bin2 + ub[Mn] + vb[t]) * LN2 + PNORM;
  } else {
    int i = t - Np1;
    if (i < Mn) ob[(size_t)i * Np1 + Nn] = (bin2 + ub[i] + vb[Nn]) * LN2 + PNORM;
  }
}

// ---------------- GEMM (fp32 inputs) — fallback paths --------------------------------------
template<typename ST>
__global__ void __launch_bounds__(256) gemm_k(
    const float* __restrict__ A, const float* __restrict__ Bm,
    ST* __restrict__ S, long srow, long sbatch)
{
  int wid  = (blockIdx.x * 256 + threadIdx.x) >> 6;
  int lane = threadIdx.x & 63;
  int b  = wid >> 10;
  int tt = wid & 1023;
  int i0 = (tt >> 5) << 6;
  int j0 = (tt & 31) << 6;
  int ln = lane & 15, qd = lane >> 4;
  const float* Ab = A  + (size_t)b * Mn * Cn;
  const float* Bb = Bm + (size_t)b * Nn * Cn;

  v4f acc[4][4];
  #pragma unroll
  for (int r = 0; r < 4; ++r)
    #pragma unroll
    for (int c = 0; c < 4; ++c)
      #pragma unroll
      for (int e = 0; e < 4; ++e) acc[r][c][e] = 0.0f;

  #pragma unroll
  for (int k0 = 0; k0 < Cn; k0 += 32){
    int kk = k0 + qd * 8;
    v8bf af[4], bfr[4];
    #pragma unroll
    for (int r = 0; r < 4; ++r){
      const float* p = Ab + (size_t)(i0 + r*16 + ln) * Cn + kk;
      v4f lo = *(const v4f*)p, hi = *(const v4f*)(p + 4);
      #pragma unroll
      for (int e = 0; e < 4; ++e){ af[r][e] = (__bf16)lo[e]; af[r][e+4] = (__bf16)hi[e]; }
    }
    #pragma unroll
    for (int c = 0; c < 4; ++c){
      const float* p = Bb + (size_t)(j0 + c*16 + ln) * Cn + kk;
      v4f lo = *(const v4f*)p, hi = *(const v4f*)(p + 4);
      #pragma unroll
      for (int e = 0; e < 4; ++e){ bfr[c][e] = (__bf16)lo[e]; bfr[c][e+4] = (__bf16)hi[e]; }
    }
    #pragma unroll
    for (int r = 0; r < 4; ++r)
      #pragma unroll
      for (int c = 0; c < 4; ++c)
        acc[r][c] = __builtin_amdgcn_mfma_f32_16x16x32_bf16(af[r], bfr[c], acc[r][c], 0, 0, 0);
  }

  ST* Sb = S + (size_t)b * sbatch;
  #pragma unroll
  for (int r = 0; r < 4; ++r){
    #pragma unroll
    for (int e = 0; e < 4; ++e){
      int row = i0 + r*16 + qd*4 + e;
      #pragma unroll
      for (int c = 0; c < 4; ++c)
        stS(Sb + (size_t)row * srow + (j0 + c*16 + ln), acc[r][c][e]);
    }
  }
}

// ---------------- R1 fastest-path kernels (ln domain, S+S^T) — fallback --------------------
__global__ void __launch_bounds__(256) row_pass_t(
    const unsigned short* __restrict__ S, const float* __restrict__ vin,
    float* __restrict__ uout, const float* __restrict__ binp)
{
  int b = blockIdx.y, t = threadIdx.x;
  const float* vb = vin + (size_t)b * UVS;
  __shared__ float red[8];
  if (blockIdx.x < Mn / 4){
    int lane = t & 63;
    int i = blockIdx.x * 4 + (t >> 6);
    const unsigned short* Sr = S + ((size_t)b * Mn + i) * Nn;
    float x[32];
    #pragma unroll
    for (int q = 0; q < 4; ++q){
      int j0 = q * 512 + lane * 8;
      v8u sv = *(const v8u*)(Sr + j0);
      v4f va = *(const v4f*)(vb + j0);
      v4f vc = *(const v4f*)(vb + j0 + 4);
      #pragma unroll
      for (int c = 0; c < 4; ++c){
        x[q*8 + c]     = bf2f(sv[c])   + va[c];
        x[q*8 + 4 + c] = bf2f(sv[c+4]) + vc[c];
      }
    }
    float mx[16];
    #pragma unroll
    for (int k = 0; k < 16; ++k) mx[k] = fmaxf(x[2*k], x[2*k+1]);
    #pragma unroll
    for (int k = 0; k < 8; ++k) mx[k] = fmaxf(mx[k], mx[k+8]);
    #pragma unroll
    for (int k = 0; k < 4; ++k) mx[k] = fmaxf(mx[k], mx[k+4]);
    float m = fmaxf(fmaxf(mx[0], mx[1]), fmaxf(mx[2], mx[3]));
    #pragma unroll
    for (int off = 32; off > 0; off >>= 1) m = fmaxf(m, __shfl_xor(m, off));
    float s0 = 0.f, s1 = 0.f, s2 = 0.f, s3 = 0.f;
    #pragma unroll
    for (int k = 0; k < 8; ++k){
      s0 += __expf(x[4*k]     - m);
      s1 += __expf(x[4*k + 1] - m);
      s2 += __expf(x[4*k + 2] - m);
      s3 += __expf(x[4*k + 3] - m);
    }
    float s = (s0 + s1) + (s2 + s3);
    #pragma unroll
    for (int off = 32; off > 0; off >>= 1) s += __shfl_xor(s, off);
    if (lane == 0){
      float M = m, Ss = s;
      comb(M, Ss, binp[0] + vb[Nn], 1.0f);
      uout[(size_t)b * UVS + i] = NORM - (M + __logf(Ss));
    }
  } else {
    float x[9];
    #pragma unroll
    for (int k = 0; k < 9; ++k){
      int j = t + k * 256;
      x[k] = (j <= Nn) ? vb[j] : -3.0e38f;
    }
    float m = x[0];
    #pragma unroll
    for (int k = 1; k < 9; ++k) m = fmaxf(m, x[k]);
    #pragma unroll
    for (int off = 32; off > 0; off >>= 1) m = fmaxf(m, __shfl_down(m, off));
    int w = t >> 6;
    if ((t & 63) == 0) red[w] = m;
    __syncthreads();
    float M = fmaxf(fmaxf(red[0], red[1]), fmaxf(red[2], red[3]));
    float s = 0.0f;
    #pragma unroll
    for (int k = 0; k < 9; ++k) s += __expf(x[k] - M);
    #pragma unroll
    for (int off = 32; off > 0; off >>= 1) s += __shfl_down(s, off);
    __syncthreads();
    if ((t & 63) == 0) red[w] = s;
    __syncthreads();
    if (t == 0){
      float Ss = red[0] + red[1] + red[2] + red[3];
      uout[(size_t)b * UVS + Mn] = LOGBIN - (binp[0] + M + __logf(Ss));
    }
  }
}

__global__ void __launch_bounds__(256) final_v(
    const unsigned short* __restrict__ S, float* __restrict__ out,
    const float* __restrict__ u, const float* __restrict__ v,
    const float* __restrict__ binp)
{
  int i = blockIdx.x, b = blockIdx.y, t = threadIdx.x;
  float bin = binp[0];
  const float* vb = v + (size_t)b * UVS;
  float ui = u[(size_t)b * UVS + i];
  float* ob = out + ((size_t)b * Mp1 + i) * Np1;
  if (i < Mn){
    const unsigned short* Sr = S + ((size_t)b * Mn + i) * Nn;
    int j0 = t * 8;
    v8u sv = *(const v8u*)(Sr + j0);
    v4f va = *(const v4f*)(vb + j0);
    v4f vc = *(const v4f*)(vb + j0 + 4);
    #pragma unroll
    for (int c = 0; c < 4; ++c) ob[j0 + c]     = bf2f(sv[c])   + ui + va[c] - NORM;
    #pragma unroll
    for (int c = 0; c < 4; ++c) ob[j0 + 4 + c] = bf2f(sv[c+4]) + ui + vc[c] - NORM;
    if (t == 0) ob[Nn] = bin + ui + vb[Nn] - NORM;
  } else {
    for (int j = t; j <= Nn; j += 256) ob[j] = bin + ui + vb[j] - NORM;
  }
}

// ============== FAST PATH (bf16 S only in workspace) ========================================
__global__ void __launch_bounds__(256) row_pass_v(
    const unsigned short* __restrict__ S, const float* __restrict__ v,
    float* __restrict__ u, const float* __restrict__ binp)
{
  int i = blockIdx.x, b = blockIdx.y, t = threadIdx.x;
  const float* vb = v + (size_t)b * UVS;
  float x[9];
  int K;
  if (i < Mn){
    const unsigned short* Sr = S + ((size_t)b * Mn + i) * Nn;
    int j0 = t * 8;
    v8u sv = *(const v8u*)(Sr + j0);
    v4f va = *(const v4f*)(vb + j0);
    v4f vc = *(const v4f*)(vb + j0 + 4);
    #pragma unroll
    for (int c = 0; c < 4; ++c){ x[c] = bf2f(sv[c]) + va[c]; x[c+4] = bf2f(sv[c+4]) + vc[c]; }
    K = 8;
  } else {
    #pragma unroll
    for (int k = 0; k < 9; ++k){
      int j = t + k * 256;
      x[k] = (j <= Nn) ? vb[j] : -3.0e38f;
    }
    K = 9;
  }
  float m = x[0];
  #pragma unroll
  for (int k = 1; k < 9; ++k) if (k < K) m = fmaxf(m, x[k]);
  #pragma unroll
  for (int off = 32; off > 0; off >>= 1) m = fmaxf(m, __shfl_down(m, off));
  __shared__ float red[8];
  int w = t >> 6;
  if ((t & 63) == 0) red[w] = m;
  __syncthreads();
  float M = fmaxf(fmaxf(red[0], red[1]), fmaxf(red[2], red[3]));
  float s = 0.0f;
  #pragma unroll
  for (int k = 0; k < 9; ++k) if (k < K) s += __expf(x[k] - M);
  #pragma unroll
  for (int off = 32; off > 0; off >>= 1) s += __shfl_down(s, off);
  __syncthreads();
  if ((t & 63) == 0) red[w] = s;
  __syncthreads();
  if (t == 0){
    float Ss = red[0] + red[1] + red[2] + red[3];
    float bin = binp[0];
    if (i < Mn){
      comb(M, Ss, bin + vb[Nn], 1.0f);
      u[(size_t)b * UVS + i] = NORM - (M + __logf(Ss));
    } else {
      u[(size_t)b * UVS + Mn] = LOGBIN - (bin + M + __logf(Ss));
    }
  }
}

__global__ void __launch_bounds__(256) col_pass_v(
    const unsigned short* __restrict__ S, const float* __restrict__ u,
    float* __restrict__ v, const float* __restrict__ binp)
{
  int blk = blockIdx.x, b = blockIdx.y, t = threadIdx.x;
  const float* ub = u + (size_t)b * UVS;
  __shared__ float lm[32][65];
  __shared__ float ls[32][65];
  __shared__ float red[16];
  if (blk < Nn / 64){
    int tx = t & 7, ty = t >> 3;
    int j0 = blk * 64 + tx * 8;
    const unsigned short* Sb = S + (size_t)b * Mn * Nn;
    float m[8], s[8];
    #pragma unroll
    for (int c = 0; c < 8; ++c){ m[c] = -3.0e38f; s[c] = 0.0f; }
    for (int i = ty; i < Mn; i += 32){
      v8u sv = *(const v8u*)(Sb + (size_t)i * Nn + j0);
      float ui = ub[i];
      #pragma unroll
      for (int c = 0; c < 8; ++c){
        float x  = bf2f(sv[c]) + ui;
        float mn = fmaxf(m[c], x);
        s[c] = s[c] * __expf(m[c] - mn) + __expf(x - mn);
        m[c] = mn;
      }
    }
    #pragma unroll
    for (int c = 0; c < 8; ++c){ lm[ty][tx*8 + c] = m[c]; ls[ty][tx*8 + c] = s[c]; }
    __syncthreads();
    if (t < 64){
      float M = -3.0e38f, Ss = 0.0f;
      #pragma unroll 4
      for (int rg = 0; rg < 32; ++rg) comb(M, Ss, lm[rg][t], ls[rg][t]);
      float bin = binp[0];
      comb(M, Ss, bin + ub[Mn], 1.0f);
      v[(size_t)b * UVS + blk * 64 + t] = NORM - (M + __logf(Ss));
    }
  } else {
    float x[9];
    #pragma unroll
    for (int k = 0; k < 9; ++k){
      int j = t + k * 256;
      x[k] = (j <= Mn) ? ub[j] : -3.0e38f;
    }
    float m = x[0];
    #pragma unroll
    for (int k = 1; k < 9; ++k) m = fmaxf(m, x[k]);
    #pragma unroll
    for (int off = 32; off > 0; off >>= 1) m = fmaxf(m, __shfl_down(m, off));
    int w = t >> 6;
    if ((t & 63) == 0) red[w] = m;
    __syncthreads();
    float M = fmaxf(fmaxf(red[0], red[1]), fmaxf(red[2], red[3]));
    float s = 0.0f;
    #pragma unroll
    for (int k = 0; k < 9; ++k) s += __expf(x[k] - M);
    #pragma unroll
    for (int off = 32; off > 0; off >>= 1) s += __shfl_down(s, off);
    __syncthreads();
    if ((t & 63) == 0) red[w] = s;
    __syncthreads();
    if (t == 0){
      float Ss = red[0] + red[1] + red[2] + red[3];
      float bin = binp[0];
      v[(size_t)b * UVS + Nn] = LOGBIN - (bin + M + __logf(Ss));
    }
  }
}

// ============== FALLBACK PATH (fp32 S in-place in d_out) ====================================
template<typename ST>
__global__ void __launch_bounds__(256) row_pass(
    const ST* __restrict__ S, long srow, long sbatch,
    const float* __restrict__ v, float* __restrict__ u,
    const float* __restrict__ binp)
{
  int i = blockIdx.x, b = blockIdx.y, t = threadIdx.x;
  const float* vb = v + (size_t)b * UVS;
  float m = -3.0e38f, s = 0.0f;
  if (i < Mn){
    const ST* Sr = S + (size_t)b * sbatch + (size_t)i * srow;
    #pragma unroll
    for (int jj = 0; jj < Nn / 256; ++jj){
      int j = jj * 256 + t;
      ons(ldS(Sr + j) + vb[j], m, s);
    }
  } else {
    for (int j = t; j <= Nn; j += 256) ons(vb[j], m, s);
  }
  #pragma unroll
  for (int off = 32; off > 0; off >>= 1){
    float m2 = __shfl_down(m, off);
    float s2 = __shfl_down(s, off);
    comb(m, s, m2, s2);
  }
  __shared__ float sm[4], ss[4];
  int w = t >> 6;
  if ((t & 63) == 0){ sm[w] = m; ss[w] = s; }
  __syncthreads();
  if (t == 0){
    #pragma unroll
    for (int w2 = 1; w2 < 4; ++w2) comb(m, s, sm[w2], ss[w2]);
    float bin = binp[0];
    if (i < Mn){
      comb(m, s, bin + vb[Nn], 1.0f);
      u[(size_t)b * UVS + i] = NORM - (m + __logf(s));
    } else {
      u[(size_t)b * UVS + Mn] = LOGBIN - (bin + m + __logf(s));
    }
  }
}

template<typename ST>
__global__ void __launch_bounds__(1024) col_pass(
    const ST* __restrict__ S, long srow, long sbatch,
    const float* __restrict__ u, float* __restrict__ v,
    const float* __restrict__ binp)
{
  int jt = blockIdx.x, b = blockIdx.y, t = threadIdx.x;
  const float* ub = u + (size_t)b * UVS;
  __shared__ float sm[16][64];
  __shared__ float ss[16][64];
  if (jt < Nn / 64){
    int c = t & 63, rg = t >> 6;
    int j = jt * 64 + c;
    const ST* Sc = S + (size_t)b * sbatch + j;
    float m = -3.0e38f, s = 0.0f;
    #pragma unroll 8
    for (int i = rg; i < Mn; i += 16)
      ons(ldS(Sc + (size_t)i * srow) + ub[i], m, s);
    sm[rg][c] = m; ss[rg][c] = s;
    __syncthreads();
    if (rg == 0){
      #pragma unroll
      for (int r = 1; r < 16; ++r) comb(m, s, sm[r][c], ss[r][c]);
      float bin = binp[0];
      comb(m, s, bin + ub[Mn], 1.0f);
      v[(size_t)b * UVS + j] = NORM - (m + __logf(s));
    }
  } else {
    float m = -3.0e38f, s = 0.0f;
    for (int i = t; i <= Mn; i += 1024) ons(ub[i], m, s);
    #pragma unroll
    for (int off = 32; off > 0; off >>= 1){
      float m2 = __shfl_down(m, off);
      float s2 = __shfl_down(s, off);
      comb(m, s, m2, s2);
    }
    int w = t >> 6;
    if ((t & 63) == 0){ sm[0][w] = m; ss[0][w] = s; }
    __syncthreads();
    if (t == 0){
      #pragma unroll
      for (int w2 = 1; w2 < 16; ++w2) comb(m, s, sm[0][w2], ss[0][w2]);
      float bin = binp[0];
      v[(size_t)b * UVS + Nn] = LOGBIN - (bin + m + __logf(s));
    }
  }
}

template<typename ST>
__global__ void __launch_bounds__(256) final_k(
    const ST* __restrict__ S, long srow, long sbatch,
    float* __restrict__ out, const float* __restrict__ u,
    const float* __restrict__ v, const float* __restrict__ binp)
{
  int i = blockIdx.x, b = blockIdx.y, t = threadIdx.x;
  float bin = binp[0];
  float ui = u[(size_t)b * UVS + i];
  const float* vb = v + (size_t)b * UVS;
  float* ob = out + ((size_t)b * Mp1 + i) * Np1;
  if (i < Mn){
    const ST* Sr = S + (size_t)b * sbatch + (size_t)i * srow;
    for (int j = t; j < Nn; j += 256)
      ob[j] = ldS(Sr + j) + ui + vb[j] - NORM;
    if (t == 0) ob[Nn] = bin + ui + vb[Nn] - NORM;
  } else {
    for (int j = t; j <= Nn; j += 256)
      ob[j] = bin + ui + vb[j] - NORM;
  }
}

__global__ void zero_uv(float* uv){
  int t = blockIdx.x * 256 + threadIdx.x;
  if (t < 2 * Bn * UVS + 64) uv[t] = 0.0f;   // u, v, and barrier words
}

extern "C" void kernel_launch(void* const* d_in, const int* in_sizes, int n_in,
                              void* d_out, int out_size, void* d_ws, size_t ws_size,
                              hipStream_t stream)
{
  const float* A    = (const float*)d_in[0];
  const float* Bm   = (const float*)d_in[1];
  const float* binp = (const float*)d_in[2];
  float* out = (float*)d_out;

  const size_t S_bytes  = (size_t)Bn * Mn * Nn * 2;      // bf16 K (64 MiB)
  const size_t AB_bytes = (size_t)Bn * Mn * Cn * 2;      // bf16 A or B (8 MiB)
  const size_t uv_bytes = (size_t)2 * Bn * UVS * 4 + 256;  // u, v, barrier
  bool useK = ws_size >= 2 * S_bytes + 2 * AB_bytes + uv_bytes;  // fastest (persistent)
  bool useT = ws_size >= 2 * S_bytes + uv_bytes;
  bool useW = ws_size >= S_bytes + uv_bytes;

  float* u;
  unsigned short* Kw  = nullptr;
  unsigned short* KTw = nullptr;
  unsigned short* Abf = nullptr;
  unsigned short* Bbf = nullptr;
  if (useK){
    Kw  = (unsigned short*)d_ws;
    KTw = (unsigned short*)((char*)d_ws + S_bytes);
    Abf = (unsigned short*)((char*)d_ws + 2 * S_bytes);
    Bbf = (unsigned short*)((char*)d_ws + 2 * S_bytes + AB_bytes);
    u   = (float*)((char*)d_ws + 2 * S_bytes + 2 * AB_bytes);
  } else if (useT){
    Kw  = (unsigned short*)d_ws;
    KTw = (unsigned short*)((char*)d_ws + S_bytes);
    u   = (float*)((char*)d_ws + 2 * S_bytes);
  } else if (useW){
    Kw = (unsigned short*)d_ws;
    u  = (float*)((char*)d_ws + S_bytes);
  } else {
    u  = (float*)d_ws;
  }
  float* v = u + (size_t)Bn * UVS;

  zero_uv<<<(2 * Bn * UVS + 64 + 255) / 256, 256, 0, stream>>>(u);

  if (useK){
    unsigned* bar = (unsigned*)(v + (size_t)Bn * UVS);   // zeroed by zero_uv
    const int cgrid = (Bn * Mn * Cn / 8) / 256;          // 2048, exact
    conv_k<<<cgrid, 256, 0, stream>>>(A,  Abf);
    conv_k<<<cgrid, 256, 0, stream>>>(Bm, Bbf);
    gemm_ke<<<(Bn * 32 * 32) / 4, 256, 0, stream>>>(Abf, Bbf, Kw, KTw);  // K and K^T fused
    sink_k<<<GRID_P, 256, 0, stream>>>(Kw, KTw, u, v, binp, bar);        // all 20 iterations
    final_g<<<(Bn * 32 * 32) / 4, 256, 0, stream>>>(Abf, Bbf, out, u, v);
    fin_edge<<<dim3(17, Bn), 256, 0, stream>>>(out, u, v, binp);
  } else if (useT){
    gemm_k<unsigned short><<<(Bn * 32 * 32) / 4, 256, 0, stream>>>(A, Bm, Kw,  Nn, (long)Mn * Nn);
    gemm_k<unsigned short><<<(Bn * 32 * 32) / 4, 256, 0, stream>>>(Bm, A, KTw, Mn, (long)Mn * Nn);
    for (int it = 0; it < SINK_ITERS; ++it){
      row_pass_t<<<dim3(Mn / 4 + 1, Bn), 256, 0, stream>>>(Kw,  v, u, binp);
      row_pass_t<<<dim3(Nn / 4 + 1, Bn), 256, 0, stream>>>(KTw, u, v, binp);
    }
    final_v<<<dim3(Mp1, Bn), 256, 0, stream>>>(Kw, out, u, v, binp);
  } else if (useW){
    gemm_k<unsigned short><<<(Bn * 32 * 32) / 4, 256, 0, stream>>>(A, Bm, Kw, Nn, (long)Mn * Nn);
    for (int it = 0; it < SINK_ITERS; ++it){
      row_pass_v<<<dim3(Mp1, Bn), 256, 0, stream>>>(Kw, v, u, binp);
      col_pass_v<<<dim3(Nn / 64 + 1, Bn), 256, 0, stream>>>(Kw, u, v, binp);
    }
    final_v<<<dim3(Mp1, Bn), 256, 0, stream>>>(Kw, out, u, v, binp);
  } else {
    const long srow = Np1, sbatch = (long)Mp1 * Np1;
    gemm_k<float><<<(Bn * 32 * 32) / 4, 256, 0, stream>>>(A, Bm, out, srow, sbatch);
    for (int it = 0; it < SINK_ITERS; ++it){
      row_pass<float><<<dim3(Mp1, Bn), 256, 0, stream>>>(out, srow, sbatch, v, u, binp);
      col_pass<float><<<dim3(Nn / 64 + 1, Bn), 1024, 0, stream>>>(out, srow, sbatch, u, v, binp);
    }
    final_k<float><<<dim3(Mp1, Bn), 256, 0, stream>>>(out, srow, sbatch, out, u, v, binp);
  }
}

// Round 11
// 782.842 us; speedup vs baseline: 5.1253x; 5.1253x over previous
//
#include <hip/hip_runtime.h>

#define Bn 8
#define Mn 2048
#define Nn 2048
#define Cn 256
#define Np1 2049
#define Mp1 2049
#define UVS 2056                        /* padded u/v row stride (16B-aligned per batch) */
#define SINK_ITERS 20
#define NORM   (-8.3177661667193428f)   /* -log(4096) */
#define LOGBIN (-0.6931471805599453f)   /* log(2048) - log(4096) */
#define LOG2E  (1.4426950408889634f)
#define LN2    (0.6931471805599453f)
#define NORM2  (-12.0f)                 /* log2(1/4096), exact */
#define LOGBIN2 (-1.0f)                 /* LOGBIN * log2e, exact */
#define PNORM  (8.3177661667193428f)    /* -NORM */

/* device transcendental shorthands: v_exp_f32 = 2^x, v_log_f32 = log2(x) */
#define EXP2(x) __builtin_amdgcn_exp2f(x)
#define LOG2(x) __builtin_amdgcn_logf(x)

typedef __bf16 v8bf __attribute__((ext_vector_type(8)));
typedef float  v4f  __attribute__((ext_vector_type(4)));
typedef unsigned short v8u __attribute__((ext_vector_type(8)));

__device__ __forceinline__ float bf2f(unsigned short h){
  return __uint_as_float(((unsigned)h) << 16);
}
__device__ __forceinline__ unsigned short f2bf(float f){
  unsigned u = __float_as_uint(f);
  return (unsigned short)((u + 0x7FFFu + ((u >> 16) & 1u)) >> 16);
}
__device__ __forceinline__ float ldS(const float* p){ return *p; }
__device__ __forceinline__ float ldS(const unsigned short* p){ return bf2f(*p); }
__device__ __forceinline__ void  stS(float* p, float x){ *p = x; }
__device__ __forceinline__ void  stS(unsigned short* p, float x){ *p = f2bf(x); }

// monotone float<->uint key for atomicMax-based fp32 max (sentinel key 0 is below all reals)
__device__ __forceinline__ unsigned fkey(float x){
  unsigned u = __float_as_uint(x);
  return (u & 0x80000000u) ? ~u : (u | 0x80000000u);
}
__device__ __forceinline__ float fdec(unsigned k){
  unsigned u = (k & 0x80000000u) ? (k ^ 0x80000000u) : ~k;
  return __uint_as_float(u);
}

// online logsumexp accumulate (ln domain; fallback paths only)
__device__ __forceinline__ void ons(float x, float& m, float& s){
  if (x <= m) { s += __expf(x - m); }
  else        { s = s * __expf(m - x) + 1.0f; m = x; }
}
__device__ __forceinline__ void comb(float& m, float& s, float m2, float s2){
  if (m2 <= m) { s += s2 * __expf(m2 - m); }
  else         { s = s * __expf(m - m2) + s2; m = m2; }
}

// ---------------- fp32 -> bf16 convert with scale (one v8 per thread, exact grid) ----------
__global__ void __launch_bounds__(256) conv_k(
    const float* __restrict__ in, unsigned short* __restrict__ out, float scale)
{
  size_t idx = (size_t)blockIdx.x * 256 + threadIdx.x;   // Bn*Mn*Cn/8 threads exactly
  const float* p = in + idx * 8;
  v4f a = *(const v4f*)p;
  v4f c = *(const v4f*)(p + 4);
  v8u o;
  #pragma unroll
  for (int e = 0; e < 4; ++e){ o[e] = f2bf(a[e] * scale); o[e+4] = f2bf(c[e] * scale); }
  *(v8u*)(out + idx * 8) = o;
}

// ---------------- GEMM (bf16 in): S2 = log2e*A.B^T, fused S2^T + fused row/col maxes -------
// Transpose staged in wave-private LDS (no barrier needed). Row/col maxes of the fp32 tile
// accumulate into rmS/rmT via monotone-key atomicMax (keys pre-zeroed = sentinel).
__global__ void __launch_bounds__(256) gemm_bt(
    const unsigned short* __restrict__ A, const unsigned short* __restrict__ Bm,
    unsigned short* __restrict__ S, unsigned short* __restrict__ ST,
    unsigned* __restrict__ rmS, unsigned* __restrict__ rmT)
{
  __shared__ unsigned short lt[4][64][65];           // 33.3 KB, wave-private 64x65 regions
  int wid  = (blockIdx.x * 256 + threadIdx.x) >> 6;  // 1 wave = one 64x64 tile
  int w    = (threadIdx.x >> 6) & 3;
  int lane = threadIdx.x & 63;
  int b  = wid >> 10;          // 32*32 = 1024 tiles per batch
  int tt = wid & 1023;
  int i0 = (tt >> 5) << 6;
  int j0 = (tt & 31) << 6;
  int ln = lane & 15, qd = lane >> 4;
  const unsigned short* Ab = A  + (size_t)b * Mn * Cn;
  const unsigned short* Bb = Bm + (size_t)b * Nn * Cn;

  v4f acc[4][4];
  #pragma unroll
  for (int r = 0; r < 4; ++r)
    #pragma unroll
    for (int c = 0; c < 4; ++c)
      #pragma unroll
      for (int e = 0; e < 4; ++e) acc[r][c][e] = 0.0f;

  #pragma unroll
  for (int k0 = 0; k0 < Cn; k0 += 32){
    int kk = k0 + qd * 8;
    v8bf af[4], bfr[4];
    #pragma unroll
    for (int r = 0; r < 4; ++r)
      af[r] = *(const v8bf*)(const void*)(Ab + (size_t)(i0 + r*16 + ln) * Cn + kk);
    #pragma unroll
    for (int c = 0; c < 4; ++c)
      bfr[c] = *(const v8bf*)(const void*)(Bb + (size_t)(j0 + c*16 + ln) * Cn + kk);
    #pragma unroll
    for (int r = 0; r < 4; ++r)
      #pragma unroll
      for (int c = 0; c < 4; ++c)
        acc[r][c] = __builtin_amdgcn_mfma_f32_16x16x32_bf16(af[r], bfr[c], acc[r][c], 0, 0, 0);
  }

  // epilogue 1: scale, write S2, stage into LDS
  unsigned short* Sb = S + (size_t)b * Mn * Nn;
  #pragma unroll
  for (int r = 0; r < 4; ++r){
    #pragma unroll
    for (int e = 0; e < 4; ++e){
      int lr = r*16 + qd*4 + e;          // C/D: col=lane&15, row=quad*4+reg  [HW-verified]
      #pragma unroll
      for (int c = 0; c < 4; ++c){
        unsigned short hv = f2bf(acc[r][c][e] * LOG2E);
        Sb[(size_t)(i0 + lr) * Nn + (j0 + c*16 + ln)] = hv;
        lt[w][lr][c*16 + ln] = hv;
      }
    }
  }
  // epilogue 2: transposed write to ST (tile lands at (j0, i0)); coalesced on ln
  unsigned short* Tb = ST + (size_t)b * Mn * Nn;
  #pragma unroll
  for (int r = 0; r < 4; ++r){
    #pragma unroll
    for (int e = 0; e < 4; ++e){
      int p = r*16 + qd*4 + e;
      #pragma unroll
      for (int c = 0; c < 4; ++c){
        int q = c*16 + ln;
        Tb[(size_t)(j0 + p) * Mn + (i0 + q)] = lt[w][q][p];
      }
    }
  }
  // epilogue 3: fused row maxes (rows of S2). Row = i0 + r*16 + qd*4 + e; its 64 cols live
  // in the 16 lanes sharing this qd (ln 0..15) x c. Reduce within the 16-lane group.
  unsigned* rS = rmS + (size_t)b * UVS;
  #pragma unroll
  for (int r = 0; r < 4; ++r){
    #pragma unroll
    for (int e = 0; e < 4; ++e){
      float m = fmaxf(fmaxf(acc[r][0][e], acc[r][1][e]), fmaxf(acc[r][2][e], acc[r][3][e]));
      m *= LOG2E;
      m = fmaxf(m, __shfl_xor(m, 1));
      m = fmaxf(m, __shfl_xor(m, 2));
      m = fmaxf(m, __shfl_xor(m, 4));
      m = fmaxf(m, __shfl_xor(m, 8));
      if (ln == 0) atomicMax(rS + (i0 + r*16 + qd*4 + e), fkey(m));
    }
  }
  // epilogue 4: fused col maxes (rows of S2^T). Col = j0 + c*16 + ln; its 64 rows live in
  // this lane's 16 (r,e) values x the 4 qd groups. Reduce in-thread then across qd.
  unsigned* rT = rmT + (size_t)b * UVS;
  #pragma unroll
  for (int c = 0; c < 4; ++c){
    float m = -3.0e38f;
    #pragma unroll
    for (int r = 0; r < 4; ++r)
      #pragma unroll
      for (int e = 0; e < 4; ++e) m = fmaxf(m, acc[r][c][e]);
    m *= LOG2E;
    m = fmaxf(m, __shfl_xor(m, 16));
    m = fmaxf(m, __shfl_xor(m, 32));
    if (qd == 0) atomicMax(rT + (j0 + c*16 + ln), fkey(m));
  }
}

// ---------------- log2-domain shifted LSE row update, 2 rows/wave (fastest path) -----------
// uout[b,i] = NORM2 - log2( sum_j 2^(S2[b,i,j] + vin[b,j]) + 2^(bin2 + vin[b,N]) )
// shift = max(rmax_i + max_j v_j, bin2 + v_N): all exp2 args <= ~0 (bf16 rounding slack).
// S2 rows read nontemporal (no L2 reuse at 64MB/pass). rmax decoded from atomicMax keys.
__global__ void __launch_bounds__(256) pass4_k(
    const unsigned short* __restrict__ S, const float* __restrict__ vin,
    float* __restrict__ uout, const unsigned* __restrict__ rmax,
    const float* __restrict__ binp)
{
  int b = blockIdx.y, t = threadIdx.x;
  const float* vb = vin + (size_t)b * UVS;
  __shared__ float red[8];
  if (blockIdx.x < Mn / 8){
    int lane = t & 63, wv = t >> 6;
    int i0 = blockIdx.x * 8 + wv * 2;          // this wave's 2 rows
    // v in registers (32 floats/lane), wave max once
    v4f va[8];
    #pragma unroll
    for (int q = 0; q < 4; ++q){
      int j0 = q * 512 + lane * 8;
      va[2*q]   = *(const v4f*)(vb + j0);
      va[2*q+1] = *(const v4f*)(vb + j0 + 4);
    }
    float mv = va[0][0];
    #pragma unroll
    for (int h = 0; h < 8; ++h)
      #pragma unroll
      for (int e = 0; e < 4; ++e) mv = fmaxf(mv, va[h][e]);
    #pragma unroll
    for (int off = 32; off > 0; off >>= 1) mv = fmaxf(mv, __shfl_xor(mv, off));
    float bin2 = binp[0] * LOG2E;
    float vN  = vb[Nn];
    float bvn = bin2 + vN;
    float sh0 = fmaxf(fdec(rmax[(size_t)b * UVS + i0])     + mv, bvn);
    float sh1 = fmaxf(fdec(rmax[(size_t)b * UVS + i0 + 1]) + mv, bvn);
    const unsigned short* Sr0 = S + ((size_t)b * Mn + i0) * Nn;
    const unsigned short* Sr1 = Sr0 + Nn;
    float a0=0.f,a1=0.f,a2=0.f,a3=0.f;
    float c0=0.f,c1=0.f,c2=0.f,c3=0.f;
    #pragma unroll
    for (int q = 0; q < 4; ++q){
      int j0 = q * 512 + lane * 8;
      v8u r0 = __builtin_nontemporal_load((const v8u*)(Sr0 + j0));
      v8u r1 = __builtin_nontemporal_load((const v8u*)(Sr1 + j0));
      a0 += EXP2(bf2f(r0[0]) + va[2*q][0]   - sh0);
      a1 += EXP2(bf2f(r0[1]) + va[2*q][1]   - sh0);
      a2 += EXP2(bf2f(r0[2]) + va[2*q][2]   - sh0);
      a3 += EXP2(bf2f(r0[3]) + va[2*q][3]   - sh0);
      c0 += EXP2(bf2f(r1[0]) + va[2*q][0]   - sh1);
      c1 += EXP2(bf2f(r1[1]) + va[2*q][1]   - sh1);
      c2 += EXP2(bf2f(r1[2]) + va[2*q][2]   - sh1);
      c3 += EXP2(bf2f(r1[3]) + va[2*q][3]   - sh1);
      a0 += EXP2(bf2f(r0[4]) + va[2*q+1][0] - sh0);
      a1 += EXP2(bf2f(r0[5]) + va[2*q+1][1] - sh0);
      a2 += EXP2(bf2f(r0[6]) + va[2*q+1][2] - sh0);
      a3 += EXP2(bf2f(r0[7]) + va[2*q+1][3] - sh0);
      c0 += EXP2(bf2f(r1[4]) + va[2*q+1][0] - sh1);
      c1 += EXP2(bf2f(r1[5]) + va[2*q+1][1] - sh1);
      c2 += EXP2(bf2f(r1[6]) + va[2*q+1][2] - sh1);
      c3 += EXP2(bf2f(r1[7]) + va[2*q+1][3] - sh1);
    }
    float sA = (a0 + a1) + (a2 + a3);
    float sB = (c0 + c1) + (c2 + c3);
    #pragma unroll
    for (int off = 32; off > 0; off >>= 1){
      sA += __shfl_xor(sA, off);
      sB += __shfl_xor(sB, off);
    }
    if (lane == 0){
      sA += EXP2(bvn - sh0);                         // dustbin column term (arg <= 0)
      sB += EXP2(bvn - sh1);
      uout[(size_t)b * UVS + i0]     = NORM2 - (sh0 + LOG2(sA));
      uout[(size_t)b * UVS + i0 + 1] = NORM2 - (sh1 + LOG2(sB));
    }
  } else {
    // dustbin row: u[M] = LOGBIN2 - (bin2 + log2 sum_j 2^(v[0..N]))
    float x[9];
    #pragma unroll
    for (int k = 0; k < 9; ++k){
      int j = t + k * 256;
      x[k] = (j <= Nn) ? vb[j] : -3.0e38f;
    }
    float m = x[0];
    #pragma unroll
    for (int k = 1; k < 9; ++k) m = fmaxf(m, x[k]);
    #pragma unroll
    for (int off = 32; off > 0; off >>= 1) m = fmaxf(m, __shfl_down(m, off));
    int w = t >> 6;
    if ((t & 63) == 0) red[w] = m;
    __syncthreads();
    float M = fmaxf(fmaxf(red[0], red[1]), fmaxf(red[2], red[3]));
    float s = 0.0f;
    #pragma unroll
    for (int k = 0; k < 9; ++k) s += EXP2(x[k] - M);
    #pragma unroll
    for (int off = 32; off > 0; off >>= 1) s += __shfl_down(s, off);
    __syncthreads();
    if ((t & 63) == 0) red[w] = s;
    __syncthreads();
    if (t == 0){
      float Ss = red[0] + red[1] + red[2] + red[3];
      float bin2 = binp[0] * LOG2E;
      uout[(size_t)b * UVS + Mn] = LOGBIN2 - (bin2 + M + LOG2(Ss));
    }
  }
}

// final (log2 domain): out = (S2 + u2 + v2)*ln2 + PNORM
__global__ void __launch_bounds__(256) final2_k(
    const unsigned short* __restrict__ S, float* __restrict__ out,
    const float* __restrict__ u, const float* __restrict__ v,
    const float* __restrict__ binp)
{
  int i = blockIdx.x, b = blockIdx.y, t = threadIdx.x;
  float bin2 = binp[0] * LOG2E;
  const float* vb = v + (size_t)b * UVS;
  float ui = u[(size_t)b * UVS + i];
  float* ob = out + ((size_t)b * Mp1 + i) * Np1;
  if (i < Mn){
    const unsigned short* Sr = S + ((size_t)b * Mn + i) * Nn;
    int j0 = t * 8;
    v8u sv = *(const v8u*)(Sr + j0);
    v4f va = *(const v4f*)(vb + j0);
    v4f vc = *(const v4f*)(vb + j0 + 4);
    #pragma unroll
    for (int c = 0; c < 4; ++c) ob[j0 + c]     = (bf2f(sv[c])   + ui + va[c]) * LN2 + PNORM;
    #pragma unroll
    for (int c = 0; c < 4; ++c) ob[j0 + 4 + c] = (bf2f(sv[c+4]) + ui + vc[c]) * LN2 + PNORM;
    if (t == 0) ob[Nn] = (bin2 + ui + vb[Nn]) * LN2 + PNORM;
  } else {
    for (int j = t; j <= Nn; j += 256) ob[j] = (bin2 + ui + vb[j]) * LN2 + PNORM;
  }
}

// ---------------- GEMM (fp32 inputs) — fallback paths --------------------------------------
template<typename ST>
__global__ void __launch_bounds__(256) gemm_k(
    const float* __restrict__ A, const float* __restrict__ Bm,
    ST* __restrict__ S, long srow, long sbatch)
{
  int wid  = (blockIdx.x * 256 + threadIdx.x) >> 6;
  int lane = threadIdx.x & 63;
  int b  = wid >> 10;
  int tt = wid & 1023;
  int i0 = (tt >> 5) << 6;
  int j0 = (tt & 31) << 6;
  int ln = lane & 15, qd = lane >> 4;
  const float* Ab = A  + (size_t)b * Mn * Cn;
  const float* Bb = Bm + (size_t)b * Nn * Cn;

  v4f acc[4][4];
  #pragma unroll
  for (int r = 0; r < 4; ++r)
    #pragma unroll
    for (int c = 0; c < 4; ++c)
      #pragma unroll
      for (int e = 0; e < 4; ++e) acc[r][c][e] = 0.0f;

  #pragma unroll
  for (int k0 = 0; k0 < Cn; k0 += 32){
    int kk = k0 + qd * 8;
    v8bf af[4], bfr[4];
    #pragma unroll
    for (int r = 0; r < 4; ++r){
      const float* p = Ab + (size_t)(i0 + r*16 + ln) * Cn + kk;
      v4f lo = *(const v4f*)p, hi = *(const v4f*)(p + 4);
      #pragma unroll
      for (int e = 0; e < 4; ++e){ af[r][e] = (__bf16)lo[e]; af[r][e+4] = (__bf16)hi[e]; }
    }
    #pragma unroll
    for (int c = 0; c < 4; ++c){
      const float* p = Bb + (size_t)(j0 + c*16 + ln) * Cn + kk;
      v4f lo = *(const v4f*)p, hi = *(const v4f*)(p + 4);
      #pragma unroll
      for (int e = 0; e < 4; ++e){ bfr[c][e] = (__bf16)lo[e]; bfr[c][e+4] = (__bf16)hi[e]; }
    }
    #pragma unroll
    for (int r = 0; r < 4; ++r)
      #pragma unroll
      for (int c = 0; c < 4; ++c)
        acc[r][c] = __builtin_amdgcn_mfma_f32_16x16x32_bf16(af[r], bfr[c], acc[r][c], 0, 0, 0);
  }

  ST* Sb = S + (size_t)b * sbatch;
  #pragma unroll
  for (int r = 0; r < 4; ++r){
    #pragma unroll
    for (int e = 0; e < 4; ++e){
      int row = i0 + r*16 + qd*4 + e;
      #pragma unroll
      for (int c = 0; c < 4; ++c)
        stS(Sb + (size_t)row * srow + (j0 + c*16 + ln), acc[r][c][e]);
    }
  }
}

// ---------------- ln-domain S+S^T kernels — fallback tier ----------------------------------
__global__ void __launch_bounds__(256) row_pass_t(
    const unsigned short* __restrict__ S, const float* __restrict__ vin,
    float* __restrict__ uout, const float* __restrict__ binp)
{
  int b = blockIdx.y, t = threadIdx.x;
  const float* vb = vin + (size_t)b * UVS;
  __shared__ float red[8];
  if (blockIdx.x < Mn / 4){
    int lane = t & 63;
    int i = blockIdx.x * 4 + (t >> 6);
    const unsigned short* Sr = S + ((size_t)b * Mn + i) * Nn;
    float x[32];
    #pragma unroll
    for (int q = 0; q < 4; ++q){
      int j0 = q * 512 + lane * 8;
      v8u sv = *(const v8u*)(Sr + j0);
      v4f va = *(const v4f*)(vb + j0);
      v4f vc = *(const v4f*)(vb + j0 + 4);
      #pragma unroll
      for (int c = 0; c < 4; ++c){
        x[q*8 + c]     = bf2f(sv[c])   + va[c];
        x[q*8 + 4 + c] = bf2f(sv[c+4]) + vc[c];
      }
    }
    float mx[16];
    #pragma unroll
    for (int k = 0; k < 16; ++k) mx[k] = fmaxf(x[2*k], x[2*k+1]);
    #pragma unroll
    for (int k = 0; k < 8; ++k) mx[k] = fmaxf(mx[k], mx[k+8]);
    #pragma unroll
    for (int k = 0; k < 4; ++k) mx[k] = fmaxf(mx[k], mx[k+4]);
    float m = fmaxf(fmaxf(mx[0], mx[1]), fmaxf(mx[2], mx[3]));
    #pragma unroll
    for (int off = 32; off > 0; off >>= 1) m = fmaxf(m, __shfl_xor(m, off));
    float s0 = 0.f, s1 = 0.f, s2 = 0.f, s3 = 0.f;
    #pragma unroll
    for (int k = 0; k < 8; ++k){
      s0 += __expf(x[4*k]     - m);
      s1 += __expf(x[4*k + 1] - m);
      s2 += __expf(x[4*k + 2] - m);
      s3 += __expf(x[4*k + 3] - m);
    }
    float s = (s0 + s1) + (s2 + s3);
    #pragma unroll
    for (int off = 32; off > 0; off >>= 1) s += __shfl_xor(s, off);
    if (lane == 0){
      float M = m, Ss = s;
      comb(M, Ss, binp[0] + vb[Nn], 1.0f);
      uout[(size_t)b * UVS + i] = NORM - (M + __logf(Ss));
    }
  } else {
    float x[9];
    #pragma unroll
    for (int k = 0; k < 9; ++k){
      int j = t + k * 256;
      x[k] = (j <= Nn) ? vb[j] : -3.0e38f;
    }
    float m = x[0];
    #pragma unroll
    for (int k = 1; k < 9; ++k) m = fmaxf(m, x[k]);
    #pragma unroll
    for (int off = 32; off > 0; off >>= 1) m = fmaxf(m, __shfl_down(m, off));
    int w = t >> 6;
    if ((t & 63) == 0) red[w] = m;
    __syncthreads();
    float M = fmaxf(fmaxf(red[0], red[1]), fmaxf(red[2], red[3]));
    float s = 0.0f;
    #pragma unroll
    for (int k = 0; k < 9; ++k) s += __expf(x[k] - M);
    #pragma unroll
    for (int off = 32; off > 0; off >>= 1) s += __shfl_down(s, off);
    __syncthreads();
    if ((t & 63) == 0) red[w] = s;
    __syncthreads();
    if (t == 0){
      float Ss = red[0] + red[1] + red[2] + red[3];
      uout[(size_t)b * UVS + Mn] = LOGBIN - (binp[0] + M + __logf(Ss));
    }
  }
}

__global__ void __launch_bounds__(256) final_v(
    const unsigned short* __restrict__ S, float* __restrict__ out,
    const float* __restrict__ u, const float* __restrict__ v,
    const float* __restrict__ binp)
{
  int i = blockIdx.x, b = blockIdx.y, t = threadIdx.x;
  float bin = binp[0];
  const float* vb = v + (size_t)b * UVS;
  float ui = u[(size_t)b * UVS + i];
  float* ob = out + ((size_t)b * Mp1 + i) * Np1;
  if (i < Mn){
    const unsigned short* Sr = S + ((size_t)b * Mn + i) * Nn;
    int j0 = t * 8;
    v8u sv = *(const v8u*)(Sr + j0);
    v4f va = *(const v4f*)(vb + j0);
    v4f vc = *(const v4f*)(vb + j0 + 4);
    #pragma unroll
    for (int c = 0; c < 4; ++c) ob[j0 + c]     = bf2f(sv[c])   + ui + va[c] - NORM;
    #pragma unroll
    for (int c = 0; c < 4; ++c) ob[j0 + 4 + c] = bf2f(sv[c+4]) + ui + vc[c] - NORM;
    if (t == 0) ob[Nn] = bin + ui + vb[Nn] - NORM;
  } else {
    for (int j = t; j <= Nn; j += 256) ob[j] = bin + ui + vb[j] - NORM;
  }
}

// ============== FAST PATH (bf16 S only in workspace) ========================================
__global__ void __launch_bounds__(256) row_pass_v(
    const unsigned short* __restrict__ S, const float* __restrict__ v,
    float* __restrict__ u, const float* __restrict__ binp)
{
  int i = blockIdx.x, b = blockIdx.y, t = threadIdx.x;
  const float* vb = v + (size_t)b * UVS;
  float x[9];
  int K;
  if (i < Mn){
    const unsigned short* Sr = S + ((size_t)b * Mn + i) * Nn;
    int j0 = t * 8;
    v8u sv = *(const v8u*)(Sr + j0);
    v4f va = *(const v4f*)(vb + j0);
    v4f vc = *(const v4f*)(vb + j0 + 4);
    #pragma unroll
    for (int c = 0; c < 4; ++c){ x[c] = bf2f(sv[c]) + va[c]; x[c+4] = bf2f(sv[c+4]) + vc[c]; }
    K = 8;
  } else {
    #pragma unroll
    for (int k = 0; k < 9; ++k){
      int j = t + k * 256;
      x[k] = (j <= Nn) ? vb[j] : -3.0e38f;
    }
    K = 9;
  }
  float m = x[0];
  #pragma unroll
  for (int k = 1; k < 9; ++k) if (k < K) m = fmaxf(m, x[k]);
  #pragma unroll
  for (int off = 32; off > 0; off >>= 1) m = fmaxf(m, __shfl_down(m, off));
  __shared__ float red[8];
  int w = t >> 6;
  if ((t & 63) == 0) red[w] = m;
  __syncthreads();
  float M = fmaxf(fmaxf(red[0], red[1]), fmaxf(red[2], red[3]));
  float s = 0.0f;
  #pragma unroll
  for (int k = 0; k < 9; ++k) if (k < K) s += __expf(x[k] - M);
  #pragma unroll
  for (int off = 32; off > 0; off >>= 1) s += __shfl_down(s, off);
  __syncthreads();
  if ((t & 63) == 0) red[w] = s;
  __syncthreads();
  if (t == 0){
    float Ss = red[0] + red[1] + red[2] + red[3];
    float bin = binp[0];
    if (i < Mn){
      comb(M, Ss, bin + vb[Nn], 1.0f);
      u[(size_t)b * UVS + i] = NORM - (M + __logf(Ss));
    } else {
      u[(size_t)b * UVS + Mn] = LOGBIN - (bin + M + __logf(Ss));
    }
  }
}

__global__ void __launch_bounds__(256) col_pass_v(
    const unsigned short* __restrict__ S, const float* __restrict__ u,
    float* __restrict__ v, const float* __restrict__ binp)
{
  int blk = blockIdx.x, b = blockIdx.y, t = threadIdx.x;
  const float* ub = u + (size_t)b * UVS;
  __shared__ float lm[32][65];
  __shared__ float ls[32][65];
  __shared__ float red[16];
  if (blk < Nn / 64){
    int tx = t & 7, ty = t >> 3;
    int j0 = blk * 64 + tx * 8;
    const unsigned short* Sb = S + (size_t)b * Mn * Nn;
    float m[8], s[8];
    #pragma unroll
    for (int c = 0; c < 8; ++c){ m[c] = -3.0e38f; s[c] = 0.0f; }
    for (int i = ty; i < Mn; i += 32){
      v8u sv = *(const v8u*)(Sb + (size_t)i * Nn + j0);
      float ui = ub[i];
      #pragma unroll
      for (int c = 0; c < 8; ++c){
        float x  = bf2f(sv[c]) + ui;
        float mn = fmaxf(m[c], x);
        s[c] = s[c] * __expf(m[c] - mn) + __expf(x - mn);
        m[c] = mn;
      }
    }
    #pragma unroll
    for (int c = 0; c < 8; ++c){ lm[ty][tx*8 + c] = m[c]; ls[ty][tx*8 + c] = s[c]; }
    __syncthreads();
    if (t < 64){
      float M = -3.0e38f, Ss = 0.0f;
      #pragma unroll 4
      for (int rg = 0; rg < 32; ++rg) comb(M, Ss, lm[rg][t], ls[rg][t]);
      float bin = binp[0];
      comb(M, Ss, bin + ub[Mn], 1.0f);
      v[(size_t)b * UVS + blk * 64 + t] = NORM - (M + __logf(Ss));
    }
  } else {
    float x[9];
    #pragma unroll
    for (int k = 0; k < 9; ++k){
      int j = t + k * 256;
      x[k] = (j <= Mn) ? ub[j] : -3.0e38f;
    }
    float m = x[0];
    #pragma unroll
    for (int k = 1; k < 9; ++k) m = fmaxf(m, x[k]);
    #pragma unroll
    for (int off = 32; off > 0; off >>= 1) m = fmaxf(m, __shfl_down(m, off));
    int w = t >> 6;
    if ((t & 63) == 0) red[w] = m;
    __syncthreads();
    float M = fmaxf(fmaxf(red[0], red[1]), fmaxf(red[2], red[3]));
    float s = 0.0f;
    #pragma unroll
    for (int k = 0; k < 9; ++k) s += __expf(x[k] - M);
    #pragma unroll
    for (int off = 32; off > 0; off >>= 1) s += __shfl_down(s, off);
    __syncthreads();
    if ((t & 63) == 0) red[w] = s;
    __syncthreads();
    if (t == 0){
      float Ss = red[0] + red[1] + red[2] + red[3];
      float bin = binp[0];
      v[(size_t)b * UVS + Nn] = LOGBIN - (bin + M + __logf(Ss));
    }
  }
}

// ============== FALLBACK PATH (fp32 S in-place in d_out) ====================================
template<typename ST>
__global__ void __launch_bounds__(256) row_pass(
    const ST* __restrict__ S, long srow, long sbatch,
    const float* __restrict__ v, float* __restrict__ u,
    const float* __restrict__ binp)
{
  int i = blockIdx.x, b = blockIdx.y, t = threadIdx.x;
  const float* vb = v + (size_t)b * UVS;
  float m = -3.0e38f, s = 0.0f;
  if (i < Mn){
    const ST* Sr = S + (size_t)b * sbatch + (size_t)i * srow;
    #pragma unroll
    for (int jj = 0; jj < Nn / 256; ++jj){
      int j = jj * 256 + t;
      ons(ldS(Sr + j) + vb[j], m, s);
    }
  } else {
    for (int j = t; j <= Nn; j += 256) ons(vb[j], m, s);
  }
  #pragma unroll
  for (int off = 32; off > 0; off >>= 1){
    float m2 = __shfl_down(m, off);
    float s2 = __shfl_down(s, off);
    comb(m, s, m2, s2);
  }
  __shared__ float sm[4], ss[4];
  int w = t >> 6;
  if ((t & 63) == 0){ sm[w] = m; ss[w] = s; }
  __syncthreads();
  if (t == 0){
    #pragma unroll
    for (int w2 = 1; w2 < 4; ++w2) comb(m, s, sm[w2], ss[w2]);
    float bin = binp[0];
    if (i < Mn){
      comb(m, s, bin + vb[Nn], 1.0f);
      u[(size_t)b * UVS + i] = NORM - (m + __logf(s));
    } else {
      u[(size_t)b * UVS + Mn] = LOGBIN - (bin + m + __logf(s));
    }
  }
}

template<typename ST>
__global__ void __launch_bounds__(1024) col_pass(
    const ST* __restrict__ S, long srow, long sbatch,
    const float* __restrict__ u, float* __restrict__ v,
    const float* __restrict__ binp)
{
  int jt = blockIdx.x, b = blockIdx.y, t = threadIdx.x;
  const float* ub = u + (size_t)b * UVS;
  __shared__ float sm[16][64];
  __shared__ float ss[16][64];
  if (jt < Nn / 64){
    int c = t & 63, rg = t >> 6;
    int j = jt * 64 + c;
    const ST* Sc = S + (size_t)b * sbatch + j;
    float m = -3.0e38f, s = 0.0f;
    #pragma unroll 8
    for (int i = rg; i < Mn; i += 16)
      ons(ldS(Sc + (size_t)i * srow) + ub[i], m, s);
    sm[rg][c] = m; ss[rg][c] = s;
    __syncthreads();
    if (rg == 0){
      #pragma unroll
      for (int r = 1; r < 16; ++r) comb(m, s, sm[r][c], ss[r][c]);
      float bin = binp[0];
      comb(m, s, bin + ub[Mn], 1.0f);
      v[(size_t)b * UVS + j] = NORM - (m + __logf(s));
    }
  } else {
    float m = -3.0e38f, s = 0.0f;
    for (int i = t; i <= Mn; i += 1024) ons(ub[i], m, s);
    #pragma unroll
    for (int off = 32; off > 0; off >>= 1){
      float m2 = __shfl_down(m, off);
      float s2 = __shfl_down(s, off);
      comb(m, s, m2, s2);
    }
    int w = t >> 6;
    if ((t & 63) == 0){ sm[0][w] = m; ss[0][w] = s; }
    __syncthreads();
    if (t == 0){
      #pragma unroll
      for (int w2 = 1; w2 < 16; ++w2) comb(m, s, sm[0][w2], ss[0][w2]);
      float bin = binp[0];
      v[(size_t)b * UVS + Nn] = LOGBIN - (bin + m + __logf(s));
    }
  }
}

template<typename ST>
__global__ void __launch_bounds__(256) final_k(
    const ST* __restrict__ S, long srow, long sbatch,
    float* __restrict__ out, const float* __restrict__ u,
    const float* __restrict__ v, const float* __restrict__ binp)
{
  int i = blockIdx.x, b = blockIdx.y, t = threadIdx.x;
  float bin = binp[0];
  float ui = u[(size_t)b * UVS + i];
  const float* vb = v + (size_t)b * UVS;
  float* ob = out + ((size_t)b * Mp1 + i) * Np1;
  if (i < Mn){
    const ST* Sr = S + (size_t)b * sbatch + (size_t)i * srow;
    for (int j = t; j < Nn; j += 256)
      ob[j] = ldS(Sr + j) + ui + vb[j] - NORM;
    if (t == 0) ob[Nn] = bin + ui + vb[Nn] - NORM;
  } else {
    for (int j = t; j <= Nn; j += 256)
      ob[j] = bin + ui + vb[j] - NORM;
  }
}

__global__ void zero_uv(float* uv){
  int t = blockIdx.x * 256 + threadIdx.x;
  if (t < 4 * Bn * UVS + 64) uv[t] = 0.0f;   // u, v, rmax keys (0 = sentinel), spare
}

extern "C" void kernel_launch(void* const* d_in, const int* in_sizes, int n_in,
                              void* d_out, int out_size, void* d_ws, size_t ws_size,
                              hipStream_t stream)
{
  const float* A    = (const float*)d_in[0];
  const float* Bm   = (const float*)d_in[1];
  const float* binp = (const float*)d_in[2];
  float* out = (float*)d_out;

  const size_t S_bytes  = (size_t)Bn * Mn * Nn * 2;      // bf16 S2 (64 MiB)
  const size_t AB_bytes = (size_t)Bn * Mn * Cn * 2;      // bf16 A or B (8 MiB)
  const size_t uv_bytes = (size_t)4 * Bn * UVS * 4 + 256;  // u, v, rmaxS, rmaxT, spare
  bool useT2 = ws_size >= 2 * S_bytes + 2 * AB_bytes + uv_bytes;  // fastest
  bool useT  = ws_size >= 2 * S_bytes + 2 * (size_t)Bn * UVS * 4;
  bool useW  = ws_size >= S_bytes + 2 * (size_t)Bn * UVS * 4;

  float* u;
  unsigned short* Sw  = nullptr;
  unsigned short* STw = nullptr;
  unsigned short* Abf = nullptr;
  unsigned short* Bbf = nullptr;
  if (useT2){
    Sw  = (unsigned short*)d_ws;
    STw = (unsigned short*)((char*)d_ws + S_bytes);
    Abf = (unsigned short*)((char*)d_ws + 2 * S_bytes);
    Bbf = (unsigned short*)((char*)d_ws + 2 * S_bytes + AB_bytes);
    u   = (float*)((char*)d_ws + 2 * S_bytes + 2 * AB_bytes);
  } else if (useT){
    Sw  = (unsigned short*)d_ws;
    STw = (unsigned short*)((char*)d_ws + S_bytes);
    u   = (float*)((char*)d_ws + 2 * S_bytes);
  } else if (useW){
    Sw = (unsigned short*)d_ws;
    u  = (float*)((char*)d_ws + S_bytes);
  } else {
    u  = (float*)d_ws;
  }
  float* v = u + (size_t)Bn * UVS;

  zero_uv<<<(4 * Bn * UVS + 64 + 255) / 256, 256, 0, stream>>>(u);

  if (useT2){
    unsigned* rmaxS = (unsigned*)(v + (size_t)Bn * UVS);
    unsigned* rmaxT = rmaxS + (size_t)Bn * UVS;
    const int cgrid = (Bn * Mn * Cn / 8) / 256;          // 2048, exact
    conv_k<<<cgrid, 256, 0, stream>>>(A,  Abf, 1.0f);
    conv_k<<<cgrid, 256, 0, stream>>>(Bm, Bbf, 1.0f);
    gemm_bt<<<(Bn * 32 * 32) / 4, 256, 0, stream>>>(Abf, Bbf, Sw, STw, rmaxS, rmaxT);
    for (int it = 0; it < SINK_ITERS; ++it){
      pass4_k<<<dim3(Mn / 8 + 1, Bn), 256, 0, stream>>>(Sw,  v, u, rmaxS, binp);  // u-update
      pass4_k<<<dim3(Nn / 8 + 1, Bn), 256, 0, stream>>>(STw, u, v, rmaxT, binp);  // v-update
    }
    final2_k<<<dim3(Mp1, Bn), 256, 0, stream>>>(Sw, out, u, v, binp);
  } else if (useT){
    gemm_k<unsigned short><<<(Bn * 32 * 32) / 4, 256, 0, stream>>>(A, Bm, Sw,  Nn, (long)Mn * Nn);
    gemm_k<unsigned short><<<(Bn * 32 * 32) / 4, 256, 0, stream>>>(Bm, A, STw, Mn, (long)Mn * Nn);
    for (int it = 0; it < SINK_ITERS; ++it){
      row_pass_t<<<dim3(Mn / 4 + 1, Bn), 256, 0, stream>>>(Sw,  v, u, binp);
      row_pass_t<<<dim3(Nn / 4 + 1, Bn), 256, 0, stream>>>(STw, u, v, binp);
    }
    final_v<<<dim3(Mp1, Bn), 256, 0, stream>>>(Sw, out, u, v, binp);
  } else if (useW){
    gemm_k<unsigned short><<<(Bn * 32 * 32) / 4, 256, 0, stream>>>(A, Bm, Sw, Nn, (long)Mn * Nn);
    for (int it = 0; it < SINK_ITERS; ++it){
      row_pass_v<<<dim3(Mp1, Bn), 256, 0, stream>>>(Sw, v, u, binp);
      col_pass_v<<<dim3(Nn / 64 + 1, Bn), 256, 0, stream>>>(Sw, u, v, binp);
    }
    final_v<<<dim3(Mp1, Bn), 256, 0, stream>>>(Sw, out, u, v, binp);
  } else {
    const long srow = Np1, sbatch = (long)Mp1 * Np1;
    gemm_k<float><<<(Bn * 32 * 32) / 4, 256, 0, stream>>>(A, Bm, out, srow, sbatch);
    for (int it = 0; it < SINK_ITERS; ++it){
      row_pass<float><<<dim3(Mp1, Bn), 256, 0, stream>>>(out, srow, sbatch, v, u, binp);
      col_pass<float><<<dim3(Nn / 64 + 1, Bn), 1024, 0, stream>>>(out, srow, sbatch, u, v, binp);
    }
    final_k<float><<<dim3(Mp1, Bn), 256, 0, stream>>>(out, srow, sbatch, out, u, v, binp);
  }
}

// Round 12
// 741.037 us; speedup vs baseline: 5.4145x; 1.0564x over previous
//
#include <hip/hip_runtime.h>

#define Bn 8
#define Mn 2048
#define Nn 2048
#define Cn 256
#define Np1 2049
#define Mp1 2049
#define UVS 2056                        /* padded u/v row stride (16B-aligned per batch) */
#define SINK_ITERS 20
#define NORM   (-8.3177661667193428f)   /* -log(4096) */
#define LOGBIN (-0.6931471805599453f)   /* log(2048) - log(4096) */
#define LOG2E  (1.4426950408889634f)
#define LN2    (0.6931471805599453f)
#define NORM2  (-12.0f)                 /* log2(1/4096), exact */
#define LOGBIN2 (-1.0f)                 /* LOGBIN * log2e, exact */
#define PNORM  (8.3177661667193428f)    /* -NORM */

/* device transcendental shorthands: v_exp_f32 = 2^x, v_log_f32 = log2(x) */
#define EXP2(x) __builtin_amdgcn_exp2f(x)
#define LOG2(x) __builtin_amdgcn_logf(x)

typedef __bf16 v8bf __attribute__((ext_vector_type(8)));
typedef float  v4f  __attribute__((ext_vector_type(4)));
typedef unsigned short v8u __attribute__((ext_vector_type(8)));

__device__ __forceinline__ float bf2f(unsigned short h){
  return __uint_as_float(((unsigned)h) << 16);
}
__device__ __forceinline__ unsigned short f2bf(float f){
  unsigned u = __float_as_uint(f);
  return (unsigned short)((u + 0x7FFFu + ((u >> 16) & 1u)) >> 16);
}
__device__ __forceinline__ float ldS(const float* p){ return *p; }
__device__ __forceinline__ float ldS(const unsigned short* p){ return bf2f(*p); }
__device__ __forceinline__ void  stS(float* p, float x){ *p = x; }
__device__ __forceinline__ void  stS(unsigned short* p, float x){ *p = f2bf(x); }

// online logsumexp accumulate (ln domain; fallback paths only)
__device__ __forceinline__ void ons(float x, float& m, float& s){
  if (x <= m) { s += __expf(x - m); }
  else        { s = s * __expf(m - x) + 1.0f; m = x; }
}
__device__ __forceinline__ void comb(float& m, float& s, float m2, float s2){
  if (m2 <= m) { s += s2 * __expf(m2 - m); }
  else         { s = s * __expf(m - m2) + s2; m = m2; }
}

// ---------------- fp32 -> bf16 convert, both inputs in one launch --------------------------
__global__ void __launch_bounds__(256) conv2_k(
    const float* __restrict__ A, const float* __restrict__ Bm,
    unsigned short* __restrict__ Ao, unsigned short* __restrict__ Bo)
{
  const size_t half = (size_t)Bn * Mn * Cn / 8;          // v8 chunks per input
  size_t idx = (size_t)blockIdx.x * 256 + threadIdx.x;   // 2*half threads exactly
  const float* in;
  unsigned short* out;
  if (idx < half){ in = A; out = Ao; }
  else           { in = Bm; out = Bo; idx -= half; }
  const float* p = in + idx * 8;
  v4f a = *(const v4f*)p;
  v4f c = *(const v4f*)(p + 4);
  v8u o;
  #pragma unroll
  for (int e = 0; e < 4; ++e){ o[e] = f2bf(a[e]); o[e+4] = f2bf(c[e]); }
  *(v8u*)(out + idx * 8) = o;
}

// ---------------- GEMM (bf16 in): S2 = log2e*A.B^T, and fused S2^T via LDS transpose -------
// Each wave owns a 64x64 tile; transpose staged in wave-private LDS (no barrier needed).
__global__ void __launch_bounds__(256) gemm_bt(
    const unsigned short* __restrict__ A, const unsigned short* __restrict__ Bm,
    unsigned short* __restrict__ S, unsigned short* __restrict__ ST)
{
  __shared__ unsigned short lt[4][64][65];           // 33.3 KB, wave-private 64x65 regions
  int wid  = (blockIdx.x * 256 + threadIdx.x) >> 6;  // 1 wave = one 64x64 tile
  int w    = (threadIdx.x >> 6) & 3;
  int lane = threadIdx.x & 63;
  int b  = wid >> 10;          // 32*32 = 1024 tiles per batch
  int tt = wid & 1023;
  int i0 = (tt >> 5) << 6;
  int j0 = (tt & 31) << 6;
  int ln = lane & 15, qd = lane >> 4;
  const unsigned short* Ab = A  + (size_t)b * Mn * Cn;
  const unsigned short* Bb = Bm + (size_t)b * Nn * Cn;

  v4f acc[4][4];
  #pragma unroll
  for (int r = 0; r < 4; ++r)
    #pragma unroll
    for (int c = 0; c < 4; ++c)
      #pragma unroll
      for (int e = 0; e < 4; ++e) acc[r][c][e] = 0.0f;

  #pragma unroll
  for (int k0 = 0; k0 < Cn; k0 += 32){
    int kk = k0 + qd * 8;
    v8bf af[4], bfr[4];
    #pragma unroll
    for (int r = 0; r < 4; ++r)
      af[r] = *(const v8bf*)(const void*)(Ab + (size_t)(i0 + r*16 + ln) * Cn + kk);
    #pragma unroll
    for (int c = 0; c < 4; ++c)
      bfr[c] = *(const v8bf*)(const void*)(Bb + (size_t)(j0 + c*16 + ln) * Cn + kk);
    #pragma unroll
    for (int r = 0; r < 4; ++r)
      #pragma unroll
      for (int c = 0; c < 4; ++c)
        acc[r][c] = __builtin_amdgcn_mfma_f32_16x16x32_bf16(af[r], bfr[c], acc[r][c], 0, 0, 0);
  }

  // epilogue 1: scale by log2e, write S2, stage bf16 tile into LDS
  unsigned short* Sb = S + (size_t)b * Mn * Nn;
  #pragma unroll
  for (int r = 0; r < 4; ++r){
    #pragma unroll
    for (int e = 0; e < 4; ++e){
      int lr = r*16 + qd*4 + e;          // C/D: col=lane&15, row=quad*4+reg  [HW-verified]
      #pragma unroll
      for (int c = 0; c < 4; ++c){
        unsigned short hv = f2bf(acc[r][c][e] * LOG2E);
        Sb[(size_t)(i0 + lr) * Nn + (j0 + c*16 + ln)] = hv;
        lt[w][lr][c*16 + ln] = hv;
      }
    }
  }
  // epilogue 2: transposed write to ST (tile lands at (j0, i0)); coalesced on ln
  unsigned short* Tb = ST + (size_t)b * Mn * Nn;
  #pragma unroll
  for (int r = 0; r < 4; ++r){
    #pragma unroll
    for (int e = 0; e < 4; ++e){
      int p = r*16 + qd*4 + e;
      #pragma unroll
      for (int c = 0; c < 4; ++c){
        int q = c*16 + ln;
        Tb[(size_t)(j0 + p) * Mn + (i0 + q)] = lt[w][q][p];
      }
    }
  }
}

// ---------------- per-row max of S2 and S2^T in one launch (one-time) ----------------------
__global__ void __launch_bounds__(256) rmax2_k(
    const unsigned short* __restrict__ S, const unsigned short* __restrict__ ST,
    float* __restrict__ rmS, float* __restrict__ rmT)
{
  int by = blockIdx.y;                   // 0..2*Bn-1: first Bn -> S, rest -> ST
  const unsigned short* Sx;
  float* rm;
  if (by < Bn){ Sx = S  + (size_t)by * Mn * Nn;        rm = rmS + (size_t)by * UVS; }
  else        { Sx = ST + (size_t)(by - Bn) * Mn * Nn; rm = rmT + (size_t)(by - Bn) * UVS; }
  int lane = threadIdx.x & 63;
  int i = blockIdx.x * 4 + (threadIdx.x >> 6);
  const unsigned short* Sr = Sx + (size_t)i * Nn;
  float m = -3.0e38f;
  #pragma unroll
  for (int q = 0; q < 4; ++q){
    v8u sv = *(const v8u*)(Sr + q * 512 + lane * 8);
    #pragma unroll
    for (int c = 0; c < 8; ++c) m = fmaxf(m, bf2f(sv[c]));
  }
  #pragma unroll
  for (int off = 32; off > 0; off >>= 1) m = fmaxf(m, __shfl_xor(m, off));
  if (lane == 0) rm[i] = m;
}

// ---------------- log2-domain shifted LSE row update, 2 rows/wave (fastest path) -----------
// uout[b,i] = NORM2 - log2( sum_j 2^(S2[b,i,j] + vin[b,j]) + 2^(bin2 + vin[b,N]) )
// shift = max(rmax_i + max_j v_j, bin2 + v_N): all exp2 args <= 0.
// v held in registers across both rows; S-loads of the 2 rows interleave for load ILP.
__global__ void __launch_bounds__(256) pass4_k(
    const unsigned short* __restrict__ S, const float* __restrict__ vin,
    float* __restrict__ uout, const float* __restrict__ rmax,
    const float* __restrict__ binp)
{
  int b = blockIdx.y, t = threadIdx.x;
  const float* vb = vin + (size_t)b * UVS;
  __shared__ float red[8];
  if (blockIdx.x < Mn / 8){
    int lane = t & 63, wv = t >> 6;
    int i0 = blockIdx.x * 8 + wv * 2;          // this wave's 2 rows
    // v in registers (32 floats/lane), wave max once
    v4f va[8];
    #pragma unroll
    for (int q = 0; q < 4; ++q){
      int j0 = q * 512 + lane * 8;
      va[2*q]   = *(const v4f*)(vb + j0);
      va[2*q+1] = *(const v4f*)(vb + j0 + 4);
    }
    float mv = va[0][0];
    #pragma unroll
    for (int h = 0; h < 8; ++h)
      #pragma unroll
      for (int e = 0; e < 4; ++e) mv = fmaxf(mv, va[h][e]);
    #pragma unroll
    for (int off = 32; off > 0; off >>= 1) mv = fmaxf(mv, __shfl_xor(mv, off));
    float bin2 = binp[0] * LOG2E;
    float vN  = vb[Nn];
    float bvn = bin2 + vN;
    float sh0 = fmaxf(rmax[(size_t)b * UVS + i0]     + mv, bvn);
    float sh1 = fmaxf(rmax[(size_t)b * UVS + i0 + 1] + mv, bvn);
    const unsigned short* Sr0 = S + ((size_t)b * Mn + i0) * Nn;
    const unsigned short* Sr1 = Sr0 + Nn;
    float a0=0.f,a1=0.f,a2=0.f,a3=0.f;
    float c0=0.f,c1=0.f,c2=0.f,c3=0.f;
    #pragma unroll
    for (int q = 0; q < 4; ++q){
      int j0 = q * 512 + lane * 8;
      v8u r0 = *(const v8u*)(Sr0 + j0);
      v8u r1 = *(const v8u*)(Sr1 + j0);
      a0 += EXP2(bf2f(r0[0]) + va[2*q][0]   - sh0);
      a1 += EXP2(bf2f(r0[1]) + va[2*q][1]   - sh0);
      a2 += EXP2(bf2f(r0[2]) + va[2*q][2]   - sh0);
      a3 += EXP2(bf2f(r0[3]) + va[2*q][3]   - sh0);
      c0 += EXP2(bf2f(r1[0]) + va[2*q][0]   - sh1);
      c1 += EXP2(bf2f(r1[1]) + va[2*q][1]   - sh1);
      c2 += EXP2(bf2f(r1[2]) + va[2*q][2]   - sh1);
      c3 += EXP2(bf2f(r1[3]) + va[2*q][3]   - sh1);
      a0 += EXP2(bf2f(r0[4]) + va[2*q+1][0] - sh0);
      a1 += EXP2(bf2f(r0[5]) + va[2*q+1][1] - sh0);
      a2 += EXP2(bf2f(r0[6]) + va[2*q+1][2] - sh0);
      a3 += EXP2(bf2f(r0[7]) + va[2*q+1][3] - sh0);
      c0 += EXP2(bf2f(r1[4]) + va[2*q+1][0] - sh1);
      c1 += EXP2(bf2f(r1[5]) + va[2*q+1][1] - sh1);
      c2 += EXP2(bf2f(r1[6]) + va[2*q+1][2] - sh1);
      c3 += EXP2(bf2f(r1[7]) + va[2*q+1][3] - sh1);
    }
    float sA = (a0 + a1) + (a2 + a3);
    float sB = (c0 + c1) + (c2 + c3);
    #pragma unroll
    for (int off = 32; off > 0; off >>= 1){
      sA += __shfl_xor(sA, off);
      sB += __shfl_xor(sB, off);
    }
    if (lane == 0){
      sA += EXP2(bvn - sh0);                         // dustbin column term (arg <= 0)
      sB += EXP2(bvn - sh1);
      uout[(size_t)b * UVS + i0]     = NORM2 - (sh0 + LOG2(sA));
      uout[(size_t)b * UVS + i0 + 1] = NORM2 - (sh1 + LOG2(sB));
    }
  } else {
    // dustbin row: u[M] = LOGBIN2 - (bin2 + log2 sum_j 2^(v[0..N]))
    float x[9];
    #pragma unroll
    for (int k = 0; k < 9; ++k){
      int j = t + k * 256;
      x[k] = (j <= Nn) ? vb[j] : -3.0e38f;
    }
    float m = x[0];
    #pragma unroll
    for (int k = 1; k < 9; ++k) m = fmaxf(m, x[k]);
    #pragma unroll
    for (int off = 32; off > 0; off >>= 1) m = fmaxf(m, __shfl_down(m, off));
    int w = t >> 6;
    if ((t & 63) == 0) red[w] = m;
    __syncthreads();
    float M = fmaxf(fmaxf(red[0], red[1]), fmaxf(red[2], red[3]));
    float s = 0.0f;
    #pragma unroll
    for (int k = 0; k < 9; ++k) s += EXP2(x[k] - M);
    #pragma unroll
    for (int off = 32; off > 0; off >>= 1) s += __shfl_down(s, off);
    __syncthreads();
    if ((t & 63) == 0) red[w] = s;
    __syncthreads();
    if (t == 0){
      float Ss = red[0] + red[1] + red[2] + red[3];
      float bin2 = binp[0] * LOG2E;
      uout[(size_t)b * UVS + Mn] = LOGBIN2 - (bin2 + M + LOG2(Ss));
    }
  }
}

// final (log2 domain): out = (S2 + u2 + v2)*ln2 + PNORM
__global__ void __launch_bounds__(256) final2_k(
    const unsigned short* __restrict__ S, float* __restrict__ out,
    const float* __restrict__ u, const float* __restrict__ v,
    const float* __restrict__ binp)
{
  int i = blockIdx.x, b = blockIdx.y, t = threadIdx.x;
  float bin2 = binp[0] * LOG2E;
  const float* vb = v + (size_t)b * UVS;
  float ui = u[(size_t)b * UVS + i];
  float* ob = out + ((size_t)b * Mp1 + i) * Np1;
  if (i < Mn){
    const unsigned short* Sr = S + ((size_t)b * Mn + i) * Nn;
    int j0 = t * 8;
    v8u sv = *(const v8u*)(Sr + j0);
    v4f va = *(const v4f*)(vb + j0);
    v4f vc = *(const v4f*)(vb + j0 + 4);
    #pragma unroll
    for (int c = 0; c < 4; ++c) ob[j0 + c]     = (bf2f(sv[c])   + ui + va[c]) * LN2 + PNORM;
    #pragma unroll
    for (int c = 0; c < 4; ++c) ob[j0 + 4 + c] = (bf2f(sv[c+4]) + ui + vc[c]) * LN2 + PNORM;
    if (t == 0) ob[Nn] = (bin2 + ui + vb[Nn]) * LN2 + PNORM;
  } else {
    for (int j = t; j <= Nn; j += 256) ob[j] = (bin2 + ui + vb[j]) * LN2 + PNORM;
  }
}

// ---------------- GEMM (fp32 inputs) — fallback paths --------------------------------------
template<typename ST>
__global__ void __launch_bounds__(256) gemm_k(
    const float* __restrict__ A, const float* __restrict__ Bm,
    ST* __restrict__ S, long srow, long sbatch)
{
  int wid  = (blockIdx.x * 256 + threadIdx.x) >> 6;
  int lane = threadIdx.x & 63;
  int b  = wid >> 10;
  int tt = wid & 1023;
  int i0 = (tt >> 5) << 6;
  int j0 = (tt & 31) << 6;
  int ln = lane & 15, qd = lane >> 4;
  const float* Ab = A  + (size_t)b * Mn * Cn;
  const float* Bb = Bm + (size_t)b * Nn * Cn;

  v4f acc[4][4];
  #pragma unroll
  for (int r = 0; r < 4; ++r)
    #pragma unroll
    for (int c = 0; c < 4; ++c)
      #pragma unroll
      for (int e = 0; e < 4; ++e) acc[r][c][e] = 0.0f;

  #pragma unroll
  for (int k0 = 0; k0 < Cn; k0 += 32){
    int kk = k0 + qd * 8;
    v8bf af[4], bfr[4];
    #pragma unroll
    for (int r = 0; r < 4; ++r){
      const float* p = Ab + (size_t)(i0 + r*16 + ln) * Cn + kk;
      v4f lo = *(const v4f*)p, hi = *(const v4f*)(p + 4);
      #pragma unroll
      for (int e = 0; e < 4; ++e){ af[r][e] = (__bf16)lo[e]; af[r][e+4] = (__bf16)hi[e]; }
    }
    #pragma unroll
    for (int c = 0; c < 4; ++c){
      const float* p = Bb + (size_t)(j0 + c*16 + ln) * Cn + kk;
      v4f lo = *(const v4f*)p, hi = *(const v4f*)(p + 4);
      #pragma unroll
      for (int e = 0; e < 4; ++e){ bfr[c][e] = (__bf16)lo[e]; bfr[c][e+4] = (__bf16)hi[e]; }
    }
    #pragma unroll
    for (int r = 0; r < 4; ++r)
      #pragma unroll
      for (int c = 0; c < 4; ++c)
        acc[r][c] = __builtin_amdgcn_mfma_f32_16x16x32_bf16(af[r], bfr[c], acc[r][c], 0, 0, 0);
  }

  ST* Sb = S + (size_t)b * sbatch;
  #pragma unroll
  for (int r = 0; r < 4; ++r){
    #pragma unroll
    for (int e = 0; e < 4; ++e){
      int row = i0 + r*16 + qd*4 + e;
      #pragma unroll
      for (int c = 0; c < 4; ++c)
        stS(Sb + (size_t)row * srow + (j0 + c*16 + ln), acc[r][c][e]);
    }
  }
}

// ---------------- ln-domain S+S^T kernels — fallback tier ----------------------------------
__global__ void __launch_bounds__(256) row_pass_t(
    const unsigned short* __restrict__ S, const float* __restrict__ vin,
    float* __restrict__ uout, const float* __restrict__ binp)
{
  int b = blockIdx.y, t = threadIdx.x;
  const float* vb = vin + (size_t)b * UVS;
  __shared__ float red[8];
  if (blockIdx.x < Mn / 4){
    int lane = t & 63;
    int i = blockIdx.x * 4 + (t >> 6);
    const unsigned short* Sr = S + ((size_t)b * Mn + i) * Nn;
    float x[32];
    #pragma unroll
    for (int q = 0; q < 4; ++q){
      int j0 = q * 512 + lane * 8;
      v8u sv = *(const v8u*)(Sr + j0);
      v4f va = *(const v4f*)(vb + j0);
      v4f vc = *(const v4f*)(vb + j0 + 4);
      #pragma unroll
      for (int c = 0; c < 4; ++c){
        x[q*8 + c]     = bf2f(sv[c])   + va[c];
        x[q*8 + 4 + c] = bf2f(sv[c+4]) + vc[c];
      }
    }
    float mx[16];
    #pragma unroll
    for (int k = 0; k < 16; ++k) mx[k] = fmaxf(x[2*k], x[2*k+1]);
    #pragma unroll
    for (int k = 0; k < 8; ++k) mx[k] = fmaxf(mx[k], mx[k+8]);
    #pragma unroll
    for (int k = 0; k < 4; ++k) mx[k] = fmaxf(mx[k], mx[k+4]);
    float m = fmaxf(fmaxf(mx[0], mx[1]), fmaxf(mx[2], mx[3]));
    #pragma unroll
    for (int off = 32; off > 0; off >>= 1) m = fmaxf(m, __shfl_xor(m, off));
    float s0 = 0.f, s1 = 0.f, s2 = 0.f, s3 = 0.f;
    #pragma unroll
    for (int k = 0; k < 8; ++k){
      s0 += __expf(x[4*k]     - m);
      s1 += __expf(x[4*k + 1] - m);
      s2 += __expf(x[4*k + 2] - m);
      s3 += __expf(x[4*k + 3] - m);
    }
    float s = (s0 + s1) + (s2 + s3);
    #pragma unroll
    for (int off = 32; off > 0; off >>= 1) s += __shfl_xor(s, off);
    if (lane == 0){
      float M = m, Ss = s;
      comb(M, Ss, binp[0] + vb[Nn], 1.0f);
      uout[(size_t)b * UVS + i] = NORM - (M + __logf(Ss));
    }
  } else {
    float x[9];
    #pragma unroll
    for (int k = 0; k < 9; ++k){
      int j = t + k * 256;
      x[k] = (j <= Nn) ? vb[j] : -3.0e38f;
    }
    float m = x[0];
    #pragma unroll
    for (int k = 1; k < 9; ++k) m = fmaxf(m, x[k]);
    #pragma unroll
    for (int off = 32; off > 0; off >>= 1) m = fmaxf(m, __shfl_down(m, off));
    int w = t >> 6;
    if ((t & 63) == 0) red[w] = m;
    __syncthreads();
    float M = fmaxf(fmaxf(red[0], red[1]), fmaxf(red[2], red[3]));
    float s = 0.0f;
    #pragma unroll
    for (int k = 0; k < 9; ++k) s += __expf(x[k] - M);
    #pragma unroll
    for (int off = 32; off > 0; off >>= 1) s += __shfl_down(s, off);
    __syncthreads();
    if ((t & 63) == 0) red[w] = s;
    __syncthreads();
    if (t == 0){
      float Ss = red[0] + red[1] + red[2] + red[3];
      uout[(size_t)b * UVS + Mn] = LOGBIN - (binp[0] + M + __logf(Ss));
    }
  }
}

__global__ void __launch_bounds__(256) final_v(
    const unsigned short* __restrict__ S, float* __restrict__ out,
    const float* __restrict__ u, const float* __restrict__ v,
    const float* __restrict__ binp)
{
  int i = blockIdx.x, b = blockIdx.y, t = threadIdx.x;
  float bin = binp[0];
  const float* vb = v + (size_t)b * UVS;
  float ui = u[(size_t)b * UVS + i];
  float* ob = out + ((size_t)b * Mp1 + i) * Np1;
  if (i < Mn){
    const unsigned short* Sr = S + ((size_t)b * Mn + i) * Nn;
    int j0 = t * 8;
    v8u sv = *(const v8u*)(Sr + j0);
    v4f va = *(const v4f*)(vb + j0);
    v4f vc = *(const v4f*)(vb + j0 + 4);
    #pragma unroll
    for (int c = 0; c < 4; ++c) ob[j0 + c]     = bf2f(sv[c])   + ui + va[c] - NORM;
    #pragma unroll
    for (int c = 0; c < 4; ++c) ob[j0 + 4 + c] = bf2f(sv[c+4]) + ui + vc[c] - NORM;
    if (t == 0) ob[Nn] = bin + ui + vb[Nn] - NORM;
  } else {
    for (int j = t; j <= Nn; j += 256) ob[j] = bin + ui + vb[j] - NORM;
  }
}

// ============== FAST PATH (bf16 S only in workspace) ========================================
__global__ void __launch_bounds__(256) row_pass_v(
    const unsigned short* __restrict__ S, const float* __restrict__ v,
    float* __restrict__ u, const float* __restrict__ binp)
{
  int i = blockIdx.x, b = blockIdx.y, t = threadIdx.x;
  const float* vb = v + (size_t)b * UVS;
  float x[9];
  int K;
  if (i < Mn){
    const unsigned short* Sr = S + ((size_t)b * Mn + i) * Nn;
    int j0 = t * 8;
    v8u sv = *(const v8u*)(Sr + j0);
    v4f va = *(const v4f*)(vb + j0);
    v4f vc = *(const v4f*)(vb + j0 + 4);
    #pragma unroll
    for (int c = 0; c < 4; ++c){ x[c] = bf2f(sv[c]) + va[c]; x[c+4] = bf2f(sv[c+4]) + vc[c]; }
    K = 8;
  } else {
    #pragma unroll
    for (int k = 0; k < 9; ++k){
      int j = t + k * 256;
      x[k] = (j <= Nn) ? vb[j] : -3.0e38f;
    }
    K = 9;
  }
  float m = x[0];
  #pragma unroll
  for (int k = 1; k < 9; ++k) if (k < K) m = fmaxf(m, x[k]);
  #pragma unroll
  for (int off = 32; off > 0; off >>= 1) m = fmaxf(m, __shfl_down(m, off));
  __shared__ float red[8];
  int w = t >> 6;
  if ((t & 63) == 0) red[w] = m;
  __syncthreads();
  float M = fmaxf(fmaxf(red[0], red[1]), fmaxf(red[2], red[3]));
  float s = 0.0f;
  #pragma unroll
  for (int k = 0; k < 9; ++k) if (k < K) s += __expf(x[k] - M);
  #pragma unroll
  for (int off = 32; off > 0; off >>= 1) s += __shfl_down(s, off);
  __syncthreads();
  if ((t & 63) == 0) red[w] = s;
  __syncthreads();
  if (t == 0){
    float Ss = red[0] + red[1] + red[2] + red[3];
    float bin = binp[0];
    if (i < Mn){
      comb(M, Ss, bin + vb[Nn], 1.0f);
      u[(size_t)b * UVS + i] = NORM - (M + __logf(Ss));
    } else {
      u[(size_t)b * UVS + Mn] = LOGBIN - (bin + M + __logf(Ss));
    }
  }
}

__global__ void __launch_bounds__(256) col_pass_v(
    const unsigned short* __restrict__ S, const float* __restrict__ u,
    float* __restrict__ v, const float* __restrict__ binp)
{
  int blk = blockIdx.x, b = blockIdx.y, t = threadIdx.x;
  const float* ub = u + (size_t)b * UVS;
  __shared__ float lm[32][65];
  __shared__ float ls[32][65];
  __shared__ float red[16];
  if (blk < Nn / 64){
    int tx = t & 7, ty = t >> 3;
    int j0 = blk * 64 + tx * 8;
    const unsigned short* Sb = S + (size_t)b * Mn * Nn;
    float m[8], s[8];
    #pragma unroll
    for (int c = 0; c < 8; ++c){ m[c] = -3.0e38f; s[c] = 0.0f; }
    for (int i = ty; i < Mn; i += 32){
      v8u sv = *(const v8u*)(Sb + (size_t)i * Nn + j0);
      float ui = ub[i];
      #pragma unroll
      for (int c = 0; c < 8; ++c){
        float x  = bf2f(sv[c]) + ui;
        float mn = fmaxf(m[c], x);
        s[c] = s[c] * __expf(m[c] - mn) + __expf(x - mn);
        m[c] = mn;
      }
    }
    #pragma unroll
    for (int c = 0; c < 8; ++c){ lm[ty][tx*8 + c] = m[c]; ls[ty][tx*8 + c] = s[c]; }
    __syncthreads();
    if (t < 64){
      float M = -3.0e38f, Ss = 0.0f;
      #pragma unroll 4
      for (int rg = 0; rg < 32; ++rg) comb(M, Ss, lm[rg][t], ls[rg][t]);
      float bin = binp[0];
      comb(M, Ss, bin + ub[Mn], 1.0f);
      v[(size_t)b * UVS + blk * 64 + t] = NORM - (M + __logf(Ss));
    }
  } else {
    float x[9];
    #pragma unroll
    for (int k = 0; k < 9; ++k){
      int j = t + k * 256;
      x[k] = (j <= Mn) ? ub[j] : -3.0e38f;
    }
    float m = x[0];
    #pragma unroll
    for (int k = 1; k < 9; ++k) m = fmaxf(m, x[k]);
    #pragma unroll
    for (int off = 32; off > 0; off >>= 1) m = fmaxf(m, __shfl_down(m, off));
    int w = t >> 6;
    if ((t & 63) == 0) red[w] = m;
    __syncthreads();
    float M = fmaxf(fmaxf(red[0], red[1]), fmaxf(red[2], red[3]));
    float s = 0.0f;
    #pragma unroll
    for (int k = 0; k < 9; ++k) s += __expf(x[k] - M);
    #pragma unroll
    for (int off = 32; off > 0; off >>= 1) s += __shfl_down(s, off);
    __syncthreads();
    if ((t & 63) == 0) red[w] = s;
    __syncthreads();
    if (t == 0){
      float Ss = red[0] + red[1] + red[2] + red[3];
      float bin = binp[0];
      v[(size_t)b * UVS + Nn] = LOGBIN - (bin + M + __logf(Ss));
    }
  }
}

// ============== FALLBACK PATH (fp32 S in-place in d_out) ====================================
template<typename ST>
__global__ void __launch_bounds__(256) row_pass(
    const ST* __restrict__ S, long srow, long sbatch,
    const float* __restrict__ v, float* __restrict__ u,
    const float* __restrict__ binp)
{
  int i = blockIdx.x, b = blockIdx.y, t = threadIdx.x;
  const float* vb = v + (size_t)b * UVS;
  float m = -3.0e38f, s = 0.0f;
  if (i < Mn){
    const ST* Sr = S + (size_t)b * sbatch + (size_t)i * srow;
    #pragma unroll
    for (int jj = 0; jj < Nn / 256; ++jj){
      int j = jj * 256 + t;
      ons(ldS(Sr + j) + vb[j], m, s);
    }
  } else {
    for (int j = t; j <= Nn; j += 256) ons(vb[j], m, s);
  }
  #pragma unroll
  for (int off = 32; off > 0; off >>= 1){
    float m2 = __shfl_down(m, off);
    float s2 = __shfl_down(s, off);
    comb(m, s, m2, s2);
  }
  __shared__ float sm[4], ss[4];
  int w = t >> 6;
  if ((t & 63) == 0){ sm[w] = m; ss[w] = s; }
  __syncthreads();
  if (t == 0){
    #pragma unroll
    for (int w2 = 1; w2 < 4; ++w2) comb(m, s, sm[w2], ss[w2]);
    float bin = binp[0];
    if (i < Mn){
      comb(m, s, bin + vb[Nn], 1.0f);
      u[(size_t)b * UVS + i] = NORM - (m + __logf(s));
    } else {
      u[(size_t)b * UVS + Mn] = LOGBIN - (bin + m + __logf(s));
    }
  }
}

template<typename ST>
__global__ void __launch_bounds__(1024) col_pass(
    const ST* __restrict__ S, long srow, long sbatch,
    const float* __restrict__ u, float* __restrict__ v,
    const float* __restrict__ binp)
{
  int jt = blockIdx.x, b = blockIdx.y, t = threadIdx.x;
  const float* ub = u + (size_t)b * UVS;
  __shared__ float sm[16][64];
  __shared__ float ss[16][64];
  if (jt < Nn / 64){
    int c = t & 63, rg = t >> 6;
    int j = jt * 64 + c;
    const ST* Sc = S + (size_t)b * sbatch + j;
    float m = -3.0e38f, s = 0.0f;
    #pragma unroll 8
    for (int i = rg; i < Mn; i += 16)
      ons(ldS(Sc + (size_t)i * srow) + ub[i], m, s);
    sm[rg][c] = m; ss[rg][c] = s;
    __syncthreads();
    if (rg == 0){
      #pragma unroll
      for (int r = 1; r < 16; ++r) comb(m, s, sm[r][c], ss[r][c]);
      float bin = binp[0];
      comb(m, s, bin + ub[Mn], 1.0f);
      v[(size_t)b * UVS + j] = NORM - (m + __logf(s));
    }
  } else {
    float m = -3.0e38f, s = 0.0f;
    for (int i = t; i <= Mn; i += 1024) ons(ub[i], m, s);
    #pragma unroll
    for (int off = 32; off > 0; off >>= 1){
      float m2 = __shfl_down(m, off);
      float s2 = __shfl_down(s, off);
      comb(m, s, m2, s2);
    }
    int w = t >> 6;
    if ((t & 63) == 0){ sm[0][w] = m; ss[0][w] = s; }
    __syncthreads();
    if (t == 0){
      #pragma unroll
      for (int w2 = 1; w2 < 16; ++w2) comb(m, s, sm[0][w2], ss[0][w2]);
      float bin = binp[0];
      v[(size_t)b * UVS + Nn] = LOGBIN - (bin + m + __logf(s));
    }
  }
}

template<typename ST>
__global__ void __launch_bounds__(256) final_k(
    const ST* __restrict__ S, long srow, long sbatch,
    float* __restrict__ out, const float* __restrict__ u,
    const float* __restrict__ v, const float* __restrict__ binp)
{
  int i = blockIdx.x, b = blockIdx.y, t = threadIdx.x;
  float bin = binp[0];
  float ui = u[(size_t)b * UVS + i];
  const float* vb = v + (size_t)b * UVS;
  float* ob = out + ((size_t)b * Mp1 + i) * Np1;
  if (i < Mn){
    const ST* Sr = S + (size_t)b * sbatch + (size_t)i * srow;
    for (int j = t; j < Nn; j += 256)
      ob[j] = ldS(Sr + j) + ui + vb[j] - NORM;
    if (t == 0) ob[Nn] = bin + ui + vb[Nn] - NORM;
  } else {
    for (int j = t; j <= Nn; j += 256)
      ob[j] = bin + ui + vb[j] - NORM;
  }
}

__global__ void zero_uv(float* uv){
  int t = blockIdx.x * 256 + threadIdx.x;
  if (t < 2 * Bn * UVS) uv[t] = 0.0f;
}

extern "C" void kernel_launch(void* const* d_in, const int* in_sizes, int n_in,
                              void* d_out, int out_size, void* d_ws, size_t ws_size,
                              hipStream_t stream)
{
  const float* A    = (const float*)d_in[0];
  const float* Bm   = (const float*)d_in[1];
  const float* binp = (const float*)d_in[2];
  float* out = (float*)d_out;

  const size_t S_bytes  = (size_t)Bn * Mn * Nn * 2;      // bf16 S2 (64 MiB)
  const size_t AB_bytes = (size_t)Bn * Mn * Cn * 2;      // bf16 A or B (8 MiB)
  const size_t uv_bytes = (size_t)4 * Bn * UVS * 4;      // u, v, rmaxS, rmaxT
  bool useT2 = ws_size >= 2 * S_bytes + 2 * AB_bytes + uv_bytes;  // fastest
  bool useT  = ws_size >= 2 * S_bytes + 2 * (size_t)Bn * UVS * 4;
  bool useW  = ws_size >= S_bytes + 2 * (size_t)Bn * UVS * 4;

  float* u;
  unsigned short* Sw  = nullptr;
  unsigned short* STw = nullptr;
  unsigned short* Abf = nullptr;
  unsigned short* Bbf = nullptr;
  if (useT2){
    Sw  = (unsigned short*)d_ws;
    STw = (unsigned short*)((char*)d_ws + S_bytes);
    Abf = (unsigned short*)((char*)d_ws + 2 * S_bytes);
    Bbf = (unsigned short*)((char*)d_ws + 2 * S_bytes + AB_bytes);
    u   = (float*)((char*)d_ws + 2 * S_bytes + 2 * AB_bytes);
  } else if (useT){
    Sw  = (unsigned short*)d_ws;
    STw = (unsigned short*)((char*)d_ws + S_bytes);
    u   = (float*)((char*)d_ws + 2 * S_bytes);
  } else if (useW){
    Sw = (unsigned short*)d_ws;
    u  = (float*)((char*)d_ws + S_bytes);
  } else {
    u  = (float*)d_ws;
  }
  float* v = u + (size_t)Bn * UVS;

  zero_uv<<<(2 * Bn * UVS + 255) / 256, 256, 0, stream>>>(u);

  if (useT2){
    float* rmaxS = v + (size_t)Bn * UVS;
    float* rmaxT = rmaxS + (size_t)Bn * UVS;
    const int cgrid = (Bn * Mn * Cn / 8) / 256;          // 2048 per input, exact
    conv2_k<<<2 * cgrid, 256, 0, stream>>>(A, Bm, Abf, Bbf);
    gemm_bt<<<(Bn * 32 * 32) / 4, 256, 0, stream>>>(Abf, Bbf, Sw, STw);  // S2 and S2^T fused
    rmax2_k<<<dim3(Mn / 4, 2 * Bn), 256, 0, stream>>>(Sw, STw, rmaxS, rmaxT);
    for (int it = 0; it < SINK_ITERS; ++it){
      pass4_k<<<dim3(Mn / 8 + 1, Bn), 256, 0, stream>>>(Sw,  v, u, rmaxS, binp);  // u-update
      pass4_k<<<dim3(Nn / 8 + 1, Bn), 256, 0, stream>>>(STw, u, v, rmaxT, binp);  // v-update
    }
    final2_k<<<dim3(Mp1, Bn), 256, 0, stream>>>(Sw, out, u, v, binp);
  } else if (useT){
    gemm_k<unsigned short><<<(Bn * 32 * 32) / 4, 256, 0, stream>>>(A, Bm, Sw,  Nn, (long)Mn * Nn);
    gemm_k<unsigned short><<<(Bn * 32 * 32) / 4, 256, 0, stream>>>(Bm, A, STw, Mn, (long)Mn * Nn);
    for (int it = 0; it < SINK_ITERS; ++it){
      row_pass_t<<<dim3(Mn / 4 + 1, Bn), 256, 0, stream>>>(Sw,  v, u, binp);
      row_pass_t<<<dim3(Nn / 4 + 1, Bn), 256, 0, stream>>>(STw, u, v, binp);
    }
    final_v<<<dim3(Mp1, Bn), 256, 0, stream>>>(Sw, out, u, v, binp);
  } else if (useW){
    gemm_k<unsigned short><<<(Bn * 32 * 32) / 4, 256, 0, stream>>>(A, Bm, Sw, Nn, (long)Mn * Nn);
    for (int it = 0; it < SINK_ITERS; ++it){
      row_pass_v<<<dim3(Mp1, Bn), 256, 0, stream>>>(Sw, v, u, binp);
      col_pass_v<<<dim3(Nn / 64 + 1, Bn), 256, 0, stream>>>(Sw, u, v, binp);
    }
    final_v<<<dim3(Mp1, Bn), 256, 0, stream>>>(Sw, out, u, v, binp);
  } else {
    const long srow = Np1, sbatch = (long)Mp1 * Np1;
    gemm_k<float><<<(Bn * 32 * 32) / 4, 256, 0, stream>>>(A, Bm, out, srow, sbatch);
    for (int it = 0; it < SINK_ITERS; ++it){
      row_pass<float><<<dim3(Mp1, Bn), 256, 0, stream>>>(out, srow, sbatch, v, u, binp);
      col_pass<float><<<dim3(Nn / 64 + 1, Bn), 1024, 0, stream>>>(out, srow, sbatch, u, v, binp);
    }
    final_k<float><<<dim3(Mp1, Bn), 256, 0, stream>>>(out, srow, sbatch, out, u, v, binp);
  }
}